// Round 9
// baseline (9291.804 us; speedup 1.0000x reference)
//
#include <hip/hip_runtime.h>
#include <cstdint>
#include <cstddef>

// Problem constants
#define NUM_C 4096
#define BB 32
#define TT 512
#define DD 128
#define MM 50

using ull = unsigned long long;

__device__ __forceinline__ float sigmoidf_(float x){ return 1.0f/(1.0f + expf(-x)); }

// Fast transcendentals on the serial critical path: v_exp_f32 / v_rcp_f32
__device__ __forceinline__ float fexp2_(float x){ return __builtin_amdgcn_exp2f(x); }
__device__ __forceinline__ float frcp_(float x){ return __builtin_amdgcn_rcpf(x); }
__device__ __forceinline__ float fast_sig_(float x){
  return frcp_(1.0f + fexp2_(-1.44269504088896341f*x));
}
__device__ __forceinline__ float fast_tanh_(float x){
  float t = fexp2_(2.88539008177792681f*x);     // e^(2x)
  return 1.0f - 2.0f*frcp_(t + 1.0f);
}

// Quad reduction via DPP (VALU pipe, no LDS): sum over lanes {x, x^1, x^2, x^3}
__device__ __forceinline__ float quadSum_(float v){
  int t = __builtin_amdgcn_update_dpp(0, __float_as_int(v), 0xB1, 0xF, 0xF, true);
  v += __int_as_float(t);
  t = __builtin_amdgcn_update_dpp(0, __float_as_int(v), 0x4E, 0xF, 0xF, true);
  v += __int_as_float(t);
  return v;
}

// Relaxed barrier: LDS visibility only (no vmcnt/expcnt drain).
__device__ __forceinline__ void barL_(){
  asm volatile("s_waitcnt lgkmcnt(0)\n\ts_barrier" ::: "memory");
}
// Drain this thread's outstanding vector-memory ops (used before publishing
// a cross-block progress flag).
__device__ __forceinline__ void waitVM_(){
  asm volatile("s_waitcnt vmcnt(0)" ::: "memory");
}

// ---------------------------------------------------------------------------
// Kernel A: parallel precompute (unchanged).
// ---------------------------------------------------------------------------
__global__ __launch_bounds__(256) void kPre(
    const int* __restrict__ q, const int* __restrict__ r,
    const float* __restrict__ k_emb, const float* __restrict__ Mk,
    const float* __restrict__ f_W, const float* __restrict__ f_b,
    const float* __restrict__ a_W, const float* __restrict__ a_b,
    float* __restrict__ wAll, ull* __restrict__ keyLo, ull* __restrict__ keyHi,
    float* __restrict__ fpre, float* __restrict__ ypre)
{
  const int b = blockIdx.y, t0 = blockIdx.x * 32, tid = threadIdx.x;
  __shared__ __align__(16) float sK[32*129];
  __shared__ int sQ[32];
  __shared__ int sR[32];
  __shared__ union UU {
    struct { float sMk[MM*129]; double sZ[32*MM]; } p2;
    float sW2[128*65];
  } u;

  if (tid < 32){ sQ[tid] = q[b*TT + t0 + tid]; sR[tid] = r[b*TT + t0 + tid]; }
  __syncthreads();
  for (int i = tid; i < 32*128; i += 256){
    int tl = i >> 7, j = i & 127;
    sK[tl*129 + j] = k_emb[(size_t)sQ[tl]*DD + j];
  }
  for (int i = tid; i < MM*128; i += 256){
    int m = i >> 7, j = i & 127;
    u.p2.sMk[m*129 + j] = Mk[i];
  }
  __syncthreads();

  for (int idx = tid; idx < 32*MM; idx += 256){
    int tl = idx / MM, m = idx - tl*MM;
    double z = 0.0;
    for (int j = 0; j < DD; j++)
      z += (double)sK[tl*129 + j] * (double)u.p2.sMk[m*129 + j];
    u.p2.sZ[tl*MM + m] = z;
  }
  __syncthreads();

  {
    int tl = tid >> 3, l8 = tid & 7;
    double zmax = -1e300;
    for (int m = l8; m < MM; m += 8) zmax = fmax(zmax, u.p2.sZ[tl*MM + m]);
    for (int s = 1; s < 8; s <<= 1) zmax = fmax(zmax, __shfl_xor(zmax, s));
    double se = 0.0;
    for (int m = l8; m < MM; m += 8){
      double e = exp(u.p2.sZ[tl*MM + m] - zmax);
      u.p2.sZ[tl*MM + m] = e;
      se += e;
    }
    for (int s = 1; s < 8; s <<= 1) se += __shfl_xor(se, s);
    double inv = 1.0 / se;
    ull klo = 0, khi = 0;
    for (int m = l8; m < MM; m += 8){
      double w = u.p2.sZ[tl*MM + m] * inv;
      wAll[((size_t)(b*TT + t0 + tl))*MM + m] = (float)w;
      double tw = fmin((w - 0.075)/(0.088 - 0.075), (1.0 - w)/(1.0 - 0.088));
      tw = fmax(tw, 0.0);
      ull iv = (tw >= 0.6) ? 2ull : ((tw >= 0.1) ? 1ull : 0ull);
      if (m < 32) klo |= iv << (2*m); else khi |= iv << (2*(m-32));
    }
    for (int s = 1; s < 8; s <<= 1){ klo |= __shfl_xor(klo, s); khi |= __shfl_xor(khi, s); }
    if (l8 == 0){ keyLo[b*TT + t0 + tl] = klo; keyHi[b*TT + t0 + tl] = khi; }
  }

  {
    const int dq = tid & 31, tq = tid >> 5;
    float acc[4][4];
    #pragma unroll
    for (int a = 0; a < 4; a++){ acc[a][0]=0.f; acc[a][1]=0.f; acc[a][2]=0.f; acc[a][3]=0.f; }
    for (int jh = 0; jh < 2; jh++){
      __syncthreads();
      for (int i = tid; i < 128*64; i += 256){
        int dd = i >> 6, jj = i & 63;
        u.sW2[dd*65 + jj] = f_W[dd*256 + 128 + jh*64 + jj];
      }
      __syncthreads();
      for (int jj = 0; jj < 64; jj++){
        float kv[4], wv[4];
        #pragma unroll
        for (int a = 0; a < 4; a++) kv[a] = sK[(tq*4 + a)*129 + jh*64 + jj];
        #pragma unroll
        for (int c = 0; c < 4; c++) wv[c] = u.sW2[(dq*4 + c)*65 + jj];
        #pragma unroll
        for (int a = 0; a < 4; a++){
          acc[a][0] += kv[a]*wv[0]; acc[a][1] += kv[a]*wv[1];
          acc[a][2] += kv[a]*wv[2]; acc[a][3] += kv[a]*wv[3];
        }
      }
    }
    #pragma unroll
    for (int a = 0; a < 4; a++){
      int tl = tq*4 + a;
      #pragma unroll
      for (int c = 0; c < 4; c++){
        int d = dq*4 + c;
        fpre[((size_t)(b*TT + t0 + tl))*DD + d] = acc[a][c] + f_b[d];
      }
    }
  }

  for (int i = tid; i < 32*DD; i += 256){
    int tl = i >> 7, d = i & 127;
    ypre[((size_t)(b*TT + t0 + tl))*DD + d] =
        a_W[(size_t)d*(NUM_C + DD) + sQ[tl]] * (float)sR[tl] + a_b[d];
  }
}

// ---------------------------------------------------------------------------
// Kernel A2: exact match search (unchanged).
// ---------------------------------------------------------------------------
__global__ __launch_bounds__(512) void kMatch(
    const ull* __restrict__ keyLo, const ull* __restrict__ keyHi, int* __restrict__ prevA)
{
  const int b = blockIdx.x, i = threadIdx.x;
  __shared__ ull slo[TT];
  __shared__ ull shi[TT];
  slo[i] = keyLo[b*TT + i];
  shi[i] = keyHi[b*TT + i];
  __syncthreads();
  const ull mylo = slo[i], myhi = shi[i];
  int found = -1;
  for (int j = i - 1; j >= 0; j--){
    if (slo[j] == mylo && shi[j] == myhi){ found = j; break; }
  }
  prevA[b*TT + i] = found;
}

// ---------------------------------------------------------------------------
// Kernel W: one-time weight products (unchanged).
// ---------------------------------------------------------------------------
__global__ __launch_bounds__(128) void kWW(
    const float* __restrict__ e_W, const float* __restrict__ add_W,
    const float* __restrict__ a_W,
    float* __restrict__ Ge, float* __restrict__ Ga)
{
  const int d = blockIdx.x;    // 0..127
  const int k = threadIdx.x;   // 0..127
  __shared__ float se[128];
  __shared__ float sa[128];
  se[k] = e_W[(size_t)d*DD + k];
  sa[k] = add_W[(size_t)d*DD + k];
  __syncthreads();
  float ge = 0.f, ga = 0.f;
  for (int j = 0; j < DD; j++){
    float af = a_W[(size_t)j*(NUM_C + DD) + NUM_C + k];
    ge += se[j]*af;
    ga += sa[j]*af;
  }
  Ge[(size_t)d*DD + k] = ge;
  Ga[(size_t)d*DD + k] = ga;
}

// ---------------------------------------------------------------------------
// Kernel EA: eapre GEMM (unchanged).
// ---------------------------------------------------------------------------
__global__ __launch_bounds__(256) void kEA(
    const float* __restrict__ ypre, const float* __restrict__ e_W,
    const float* __restrict__ add_W, const float* __restrict__ e_b,
    const float* __restrict__ add_b, float* __restrict__ eapre)
{
  const int jt = blockIdx.x;   // 0..3  (64 output cols each)
  const int rt = blockIdx.y;   // 0..511 (32 rows each)
  const int tid = threadIdx.x;
  __shared__ float sW[64*129];
  __shared__ float sF[32*129];
  for (int i = tid; i < 64*128; i += 256){
    int jj = i >> 7, k = i & 127;
    int j = jt*64 + jj;
    sW[jj*129 + k] = (j < 128) ? e_W[(size_t)j*DD + k] : add_W[(size_t)(j-128)*DD + k];
  }
  for (int i = tid; i < 32*128; i += 256){
    int rr = i >> 7, k = i & 127;
    sF[rr*129 + k] = ypre[(size_t)(rt*32 + rr)*DD + k];
  }
  __syncthreads();
  const int jq = tid & 31, rq = tid >> 5;
  float acc[4][2];
  #pragma unroll
  for (int a = 0; a < 4; a++){ acc[a][0] = 0.f; acc[a][1] = 0.f; }
  for (int k = 0; k < 128; k++){
    float fv[4], wv[2];
    #pragma unroll
    for (int a = 0; a < 4; a++) fv[a] = sF[(rq*4 + a)*129 + k];
    wv[0] = sW[(jq*2 + 0)*129 + k];
    wv[1] = sW[(jq*2 + 1)*129 + k];
    #pragma unroll
    for (int a = 0; a < 4; a++){ acc[a][0] += fv[a]*wv[0]; acc[a][1] += fv[a]*wv[1]; }
  }
  #pragma unroll
  for (int a = 0; a < 4; a++){
    int rowi = rt*32 + rq*4 + a;
    #pragma unroll
    for (int c = 0; c < 2; c++){
      int j = jt*64 + jq*2 + c;
      float bj = (j < 128) ? e_b[j] : add_b[j - 128];
      eapre[(size_t)rowi*256 + j] = acc[a][c] + bj;
    }
  }
}

// ---------------------------------------------------------------------------
// Kernel W4: repack Wih (512x128 row-major) into k-major float4 tiles:
//   Wih4[k4][j][kk] = Wih[j][k4*4+kk]   (float index k4*2048 + j*4 + kk)
// ---------------------------------------------------------------------------
__global__ __launch_bounds__(256) void kWih4(
    const float* __restrict__ Wih, float* __restrict__ Wih4)
{
  int idx = blockIdx.x*256 + threadIdx.x;     // 0..65535
  int j = idx >> 7, k = idx & 127;
  Wih4[(size_t)(k >> 2)*2048 + j*4 + (k & 3)] = Wih[idx];
}

// ---------------------------------------------------------------------------
// Kernel F (R13): FUSED pipeline with interleaved consumer GEMM.
// Blocks 0..31  : memory-recurrence role (identical to R12).
// Blocks 32..63 : LSTM role. Chunk ch's iteration:
//    - stage fAll chunk ch+1 (agent loads; flag usually already set)
//    - run 8 LSTM steps on gbuf[ch&1], with 4 k4-iterations of the NEXT
//      chunk's gates GEMM embedded in each step's barrier region (the
//      GEMM's 1024 independent FMAs fill the LSTM's DPP/LDS/transcendental
//      stall slots); step 7 writes gacc -> gbuf[(ch+1)&1].
// launch_bounds(512,1): one block/CU -> VGPR cap 256/wave (R9's spill was
// the (512,2) 128-cap); waves_per_eu(2,2) keeps the 2-wave/SIMD layout.
// ---------------------------------------------------------------------------
__global__ __launch_bounds__(512, 1) __attribute__((amdgpu_waves_per_eu(2, 2)))
void kFused(
    const float* __restrict__ wAll, const float* __restrict__ fpre,
    const float* __restrict__ eapre, const float* __restrict__ f_W,
    const float* __restrict__ Ge, const float* __restrict__ Ga,
    const float* __restrict__ Mv0, float* __restrict__ fAll,
    const float* __restrict__ Wih4, const float* __restrict__ bih,
    const float* __restrict__ bhh, const int* __restrict__ prevA,
    const float* __restrict__ Whh, float* __restrict__ Hh,
    float* __restrict__ Ch, int* __restrict__ prog)
{
  const int tid = threadIdx.x;
  const int b = blockIdx.x & 31;
  const size_t base = (size_t)b*TT;

  __shared__ __align__(16) union SU {
    struct {
      float bufR[144]; float bufF[144]; float sW9[9*52];
      float sF8[8*128]; float sEA8[8*256]; float fO8[8*128];
    } m;
    struct {
      float xh[2][144]; float gbuf[2][8*512]; int spv[TT];
      float hRing[8*128]; float cRing[8*128]; float sFc[8*128];
    } l;
  } su;

  if (blockIdx.x < 32){
    // ==================== memory-recurrence role (R11/R12) ====================
    const int dd = tid >> 2, kc = tid & 3, m0 = kc*13;
    const int wslot = (dd >> 5)*36 + (dd & 31);

    float mv[13];
    #pragma unroll
    for (int i = 0; i < 13; i++){
      int m = m0 + i;
      mv[i] = (m < MM) ? Mv0[(size_t)m*DD + dd] : 0.f;
    }
    float wf[32], ge[32], ga[32];
    {
      const float4* p;
      p = reinterpret_cast<const float4*>(&f_W[dd*256 + kc*32]);
      #pragma unroll
      for (int i = 0; i < 8; i++){ float4 v = p[i]; wf[4*i]=v.x; wf[4*i+1]=v.y; wf[4*i+2]=v.z; wf[4*i+3]=v.w; }
      p = reinterpret_cast<const float4*>(&Ge[(size_t)dd*DD + kc*32]);
      #pragma unroll
      for (int i = 0; i < 8; i++){ float4 v = p[i]; ge[4*i]=v.x; ge[4*i+1]=v.y; ge[4*i+2]=v.z; ge[4*i+3]=v.w; }
      p = reinterpret_cast<const float4*>(&Ga[(size_t)dd*DD + kc*32]);
      #pragma unroll
      for (int i = 0; i < 8; i++){ float4 v = p[i]; ga[4*i]=v.x; ga[4*i+1]=v.y; ga[4*i+2]=v.z; ga[4*i+3]=v.w; }
    }

    const int rr0 = tid / 50, mm0 = tid - rr0*50;   // valid when tid < 450
    if (tid < 18){ int rr = tid >> 1; su.m.sW9[rr*52 + 50 + (tid & 1)] = 0.f; }

    float4 pF = {0.f,0.f,0.f,0.f}, pEA = {0.f,0.f,0.f,0.f};
    float pW = 0.f;
    if (tid < 256) pF = reinterpret_cast<const float4*>(&fpre[base*DD])[tid];
    pEA = reinterpret_cast<const float4*>(&eapre[base*256])[tid];
    if (tid < 450) pW = wAll[(base + rr0)*MM + mm0];

    float wreg[13];

    for (int ch = 0; ch < TT/8; ch++){
      const int t0 = ch*8;
      if (ch){
        if (tid < 256){
          float4 v = reinterpret_cast<const float4*>(su.m.fO8)[tid];
          float* dst = &fAll[(base + t0 - 8)*DD + tid*4];
          __hip_atomic_store(dst+0, v.x, __ATOMIC_RELAXED, __HIP_MEMORY_SCOPE_AGENT);
          __hip_atomic_store(dst+1, v.y, __ATOMIC_RELAXED, __HIP_MEMORY_SCOPE_AGENT);
          __hip_atomic_store(dst+2, v.z, __ATOMIC_RELAXED, __HIP_MEMORY_SCOPE_AGENT);
          __hip_atomic_store(dst+3, v.w, __ATOMIC_RELAXED, __HIP_MEMORY_SCOPE_AGENT);
        }
      }
      if (tid < 256) reinterpret_cast<float4*>(su.m.sF8)[tid] = pF;
      reinterpret_cast<float4*>(su.m.sEA8)[tid] = pEA;
      if (tid < 450) su.m.sW9[rr0*52 + mm0] = pW;
      if (ch && tid < 256) waitVM_();     // chunk stores complete before flag
      if (t0 + 8 < TT){
        if (tid < 256) pF = reinterpret_cast<const float4*>(&fpre[(base + t0 + 8)*DD])[tid];
        pEA = reinterpret_cast<const float4*>(&eapre[(base + t0 + 8)*256])[tid];
        if (tid < 450) pW = (t0 + 8 + rr0 < TT) ? wAll[(base + t0 + 8 + rr0)*MM + mm0] : 0.f;
      }
      barL_();   // R: chunk published (and all chunk stores drained)
      if (ch && tid == 0)
        __hip_atomic_store(&prog[b], ch, __ATOMIC_RELAXED, __HIP_MEMORY_SCOPE_AGENT);

      if (ch == 0){
        #pragma unroll
        for (int i = 0; i < 13; i++) wreg[i] = su.m.sW9[m0 + i];
        float r = 0.f;
        #pragma unroll
        for (int i = 0; i < 13; i++) r += wreg[i]*mv[i];
        r = quadSum_(r);
        if (kc == 0) su.m.bufR[wslot] = r;
        barL_();
      }

      #pragma unroll
      for (int tc = 0; tc < 8; tc++){
        float wn[13];
        #pragma unroll
        for (int i = 0; i < 13; i++) wn[i] = su.m.sW9[(tc+1)*52 + m0 + i];

        // ---- stage F: f = tanh(read @ f_Wr.T + fpre) ----
        {
          const float4* x4 = reinterpret_cast<const float4*>(&su.m.bufR[kc*36]);
          float a0=0.f,a1=0.f,a2=0.f,a3=0.f;
          #pragma unroll
          for (int i = 0; i < 8; i++){
            float4 xv = x4[i];
            a0 += xv.x*wf[4*i]; a1 += xv.y*wf[4*i+1]; a2 += xv.z*wf[4*i+2]; a3 += xv.w*wf[4*i+3];
          }
          float s = quadSum_((a0+a1)+(a2+a3));
          float fval = fast_tanh_(s + su.m.sF8[tc*128 + dd]);
          if (kc == 0){
            su.m.bufF[wslot] = fval;
            su.m.fO8[tc*128 + dd] = fval;
          }
        }
        barL_();   // B

        // ---- stage EA: e,a from f; mv update; read_{t+1} = wn . mv_new ----
        {
          const float4* x4 = reinterpret_cast<const float4*>(&su.m.bufF[kc*36]);
          float e0=0.f,e1=0.f,g0=0.f,g1=0.f;
          #pragma unroll
          for (int i = 0; i < 8; i++){
            float4 xv = x4[i];
            e0 += xv.x*ge[4*i];   e1 += xv.y*ge[4*i+1];
            e0 += xv.z*ge[4*i+2]; e1 += xv.w*ge[4*i+3];
            g0 += xv.x*ga[4*i];   g1 += xv.y*ga[4*i+1];
            g0 += xv.z*ga[4*i+2]; g1 += xv.w*ga[4*i+3];
          }
          float ep = quadSum_(e0 + e1);
          float ap = quadSum_(g0 + g1);
          float e_d = fast_sig_(ep + su.m.sEA8[tc*256 + dd]);
          float a_d = fast_tanh_(ap + su.m.sEA8[tc*256 + 128 + dd]);
          float rp0 = 0.f, rp1 = 0.f;
          #pragma unroll
          for (int i = 0; i < 13; i++){
            float t = __builtin_fmaf(-e_d, mv[i], a_d);
            mv[i] = __builtin_fmaf(wreg[i], t, mv[i]);
            if (i & 1) rp1 = __builtin_fmaf(wn[i], mv[i], rp1);
            else       rp0 = __builtin_fmaf(wn[i], mv[i], rp0);
          }
          float rd = quadSum_(rp0 + rp1);
          if (kc == 0) su.m.bufR[wslot] = rd;
        }
        #pragma unroll
        for (int i = 0; i < 13; i++) wreg[i] = wn[i];
        barL_();   // C
      }
    }

    // tail: store last chunk + final flag
    if (tid < 256){
      float4 v = reinterpret_cast<const float4*>(su.m.fO8)[tid];
      float* dst = &fAll[(base + TT - 8)*DD + tid*4];
      __hip_atomic_store(dst+0, v.x, __ATOMIC_RELAXED, __HIP_MEMORY_SCOPE_AGENT);
      __hip_atomic_store(dst+1, v.y, __ATOMIC_RELAXED, __HIP_MEMORY_SCOPE_AGENT);
      __hip_atomic_store(dst+2, v.z, __ATOMIC_RELAXED, __HIP_MEMORY_SCOPE_AGENT);
      __hip_atomic_store(dst+3, v.w, __ATOMIC_RELAXED, __HIP_MEMORY_SCOPE_AGENT);
      waitVM_();
    }
    __syncthreads();
    if (tid == 0)
      __hip_atomic_store(&prog[b], TT/8, __ATOMIC_RELAXED, __HIP_MEMORY_SCOPE_AGENT);

  } else {
    // ==================== LSTM role (interleaved next-chunk GEMM) ============
    const int jo = tid >> 2, kc = tid & 3;
    const int wslot = (jo >> 5)*36 + (jo & 31);

    float whh[4][32];
    #pragma unroll
    for (int g = 0; g < 4; g++){
      const float4* W4 = reinterpret_cast<const float4*>(&Whh[(size_t)(g*128 + jo)*128 + kc*32]);
      #pragma unroll
      for (int i = 0; i < 8; i++){
        float4 v = W4[i];
        whh[g][4*i] = v.x; whh[g][4*i+1] = v.y; whh[g][4*i+2] = v.z; whh[g][4*i+3] = v.w;
      }
    }
    const float biasj = bih[tid] + bhh[tid];   // thread owns gate-column j = tid

    su.l.spv[tid] = prevA[base + tid];
    if (tid < DD) su.l.xh[0][(tid >> 5)*36 + (tid & 31)] = 0.f;

    float cin_cur = 0.f;
    float gacc[8];
    #pragma unroll
    for (int u = 0; u < 8; u++) gacc[u] = 0.f;

    // ---- prologue: stage chunk 0, full GEMM(0) -> gbuf[0] ----
    if (tid == 0){
      while (__hip_atomic_load(&prog[b], __ATOMIC_ACQUIRE, __HIP_MEMORY_SCOPE_AGENT) < 1)
        __builtin_amdgcn_s_sleep(2);
    }
    __syncthreads();
    if (tid < 256){
      const float* src = &fAll[base*DD + tid*4];
      float x0 = __hip_atomic_load(src+0, __ATOMIC_RELAXED, __HIP_MEMORY_SCOPE_AGENT);
      float x1 = __hip_atomic_load(src+1, __ATOMIC_RELAXED, __HIP_MEMORY_SCOPE_AGENT);
      float x2 = __hip_atomic_load(src+2, __ATOMIC_RELAXED, __HIP_MEMORY_SCOPE_AGENT);
      float x3 = __hip_atomic_load(src+3, __ATOMIC_RELAXED, __HIP_MEMORY_SCOPE_AGENT);
      su.l.sFc[tid*4+0] = x0; su.l.sFc[tid*4+1] = x1;
      su.l.sFc[tid*4+2] = x2; su.l.sFc[tid*4+3] = x3;
    }
    barL_();
    {
      float acc[8];
      #pragma unroll
      for (int u = 0; u < 8; u++) acc[u] = 0.f;
      for (int k4 = 0; k4 < 32; k4++){
        float4 wv = reinterpret_cast<const float4*>(Wih4)[k4*512 + tid];
        #pragma unroll
        for (int u = 0; u < 8; u++){
          float4 fv = *reinterpret_cast<const float4*>(&su.l.sFc[u*128 + k4*4]);
          acc[u] += fv.x*wv.x; acc[u] += fv.y*wv.y;
          acc[u] += fv.z*wv.z; acc[u] += fv.w*wv.w;
        }
      }
      #pragma unroll
      for (int u = 0; u < 8; u++) su.l.gbuf[0][u*512 + tid] = acc[u] + biasj;
    }

    for (int ch = 0; ch < TT/8; ch++){
      const int t0 = ch*8;
      const int pb = ch & 1;
      if (ch) __syncthreads();   // drains Hh/Ch stores; orders sFc/gbuf reuse

      // stage chunk ch+1 into sFc (producer is typically ahead -> no spin)
      if (ch + 1 < TT/8){
        if (tid == 0){
          while (__hip_atomic_load(&prog[b], __ATOMIC_ACQUIRE, __HIP_MEMORY_SCOPE_AGENT) < ch + 2)
            __builtin_amdgcn_s_sleep(2);
        }
        __syncthreads();
        if (tid < 256){
          const float* src = &fAll[(base + t0 + 8)*DD + tid*4];
          float x0 = __hip_atomic_load(src+0, __ATOMIC_RELAXED, __HIP_MEMORY_SCOPE_AGENT);
          float x1 = __hip_atomic_load(src+1, __ATOMIC_RELAXED, __HIP_MEMORY_SCOPE_AGENT);
          float x2 = __hip_atomic_load(src+2, __ATOMIC_RELAXED, __HIP_MEMORY_SCOPE_AGENT);
          float x3 = __hip_atomic_load(src+3, __ATOMIC_RELAXED, __HIP_MEMORY_SCOPE_AGENT);
          su.l.sFc[tid*4+0] = x0; su.l.sFc[tid*4+1] = x1;
          su.l.sFc[tid*4+2] = x2; su.l.sFc[tid*4+3] = x3;
        }
      }
      barL_();   // sFc(ch+1) + gbuf[pb] ready

      #pragma unroll
      for (int tc = 0; tc < 8; tc++){
        const int t = t0 + tc, p = t & 1;
        if (tc) barL_();                 // xh[p] + ring ready

        int pv2 = -1; float preH = 0.f, preC = 0.f;
        if (t + 1 < TT){
          pv2 = su.l.spv[t + 1];
          if (pv2 >= 0 && pv2 < t){
            if (pv2 >= t0){              // in-chunk: LDS ring
              preH = su.l.hRing[(pv2 & 7)*128 + jo];
              preC = su.l.cRing[(pv2 & 7)*128 + jo];
            } else {                     // older chunk: global (same block wrote it)
              preH = Hh[(base + pv2)*DD + jo];
              preC = Ch[(base + pv2)*DD + jo];
            }
          }
        }

        float gp0 = su.l.gbuf[pb][tc*512 + jo];
        float gp1 = su.l.gbuf[pb][tc*512 + 128 + jo];
        float gp2 = su.l.gbuf[pb][tc*512 + 256 + jo];
        float gp3 = su.l.gbuf[pb][tc*512 + 384 + jo];

        float a0=0.f,a1=0.f,a2=0.f,a3=0.f;
        {
          const float4* x4 = reinterpret_cast<const float4*>(&su.l.xh[p][kc*36]);
          #pragma unroll
          for (int i = 0; i < 8; i++){
            float4 xv = x4[i];
            a0 += xv.x*whh[0][4*i]; a0 += xv.y*whh[0][4*i+1]; a0 += xv.z*whh[0][4*i+2]; a0 += xv.w*whh[0][4*i+3];
            a1 += xv.x*whh[1][4*i]; a1 += xv.y*whh[1][4*i+1]; a1 += xv.z*whh[1][4*i+2]; a1 += xv.w*whh[1][4*i+3];
            a2 += xv.x*whh[2][4*i]; a2 += xv.y*whh[2][4*i+1]; a2 += xv.z*whh[2][4*i+2]; a2 += xv.w*whh[2][4*i+3];
            a3 += xv.x*whh[3][4*i]; a3 += xv.y*whh[3][4*i+1]; a3 += xv.z*whh[3][4*i+2]; a3 += xv.w*whh[3][4*i+3];
          }
        }
        a0 = quadSum_(a0); a1 = quadSum_(a1); a2 = quadSum_(a2); a3 = quadSum_(a3);

        const float ig = gp0 + a0, fg = gp1 + a1, gg = gp2 + a2, og = gp3 + a3;
        const float cn = fast_sig_(fg)*cin_cur + fast_sig_(ig)*fast_tanh_(gg);
        const float hn = fast_sig_(og)*fast_tanh_(cn);

        if (kc == 0){
          Hh[(base + t)*DD + jo] = hn;
          Ch[(base + t)*DD + jo] = cn;
          su.l.hRing[(t & 7)*128 + jo] = hn;
          su.l.cRing[(t & 7)*128 + jo] = cn;
        }

        float hin_n, cin_n;
        if (pv2 < 0 || pv2 >= t){ hin_n = hn; cin_n = cn; }       // carry
        else                     { hin_n = preH; cin_n = preC; }   // skip
        if (kc == 0) su.l.xh[1 - p][wslot] = hin_n;
        cin_cur = cin_n;

        // ---- interleaved GEMM(ch+1): k4 = 4*tc .. 4*tc+3 (independent
        //      FMAs fill this region's DPP/LDS/transcendental stalls) ----
        #pragma unroll
        for (int kk = 0; kk < 4; kk++){
          const int k4 = tc*4 + kk;
          float4 wv = reinterpret_cast<const float4*>(Wih4)[k4*512 + tid];
          #pragma unroll
          for (int u = 0; u < 8; u++){
            float4 fv = *reinterpret_cast<const float4*>(&su.l.sFc[u*128 + k4*4]);
            gacc[u] += fv.x*wv.x; gacc[u] += fv.y*wv.y;
            gacc[u] += fv.z*wv.z; gacc[u] += fv.w*wv.w;
          }
        }
        if (tc == 7){
          #pragma unroll
          for (int u = 0; u < 8; u++){
            su.l.gbuf[1 - pb][u*512 + tid] = gacc[u] + biasj;
            gacc[u] = 0.f;
          }
        }
      }
    }
  }
}

// ---------------------------------------------------------------------------
// Kernel E: output head (unchanged).
// ---------------------------------------------------------------------------
__global__ __launch_bounds__(256) void kOut(
    const float* __restrict__ Hh, const float* __restrict__ p_W,
    const float* __restrict__ p_b, float* __restrict__ out)
{
  const int row = blockIdx.x*16 + (threadIdx.x >> 4);
  const int l = threadIdx.x & 15;
  const float4* h4 = reinterpret_cast<const float4*>(&Hh[(size_t)row*DD + l*8]);
  const float4* w4 = reinterpret_cast<const float4*>(&p_W[l*8]);
  float4 ha = h4[0], hb = h4[1], wa = w4[0], wb = w4[1];
  float s = ha.x*wa.x + ha.y*wa.y + ha.z*wa.z + ha.w*wa.w
          + hb.x*wb.x + hb.y*wb.y + hb.z*wb.z + hb.w*wb.w;
  s += __shfl_xor(s, 1); s += __shfl_xor(s, 2);
  s += __shfl_xor(s, 4); s += __shfl_xor(s, 8);
  if (l == 0) out[row] = sigmoidf_(s + p_b[0]);
}

// ---------------------------------------------------------------------------
// Launch.
// ---------------------------------------------------------------------------
extern "C" void kernel_launch(void* const* d_in, const int* in_sizes, int n_in,
                              void* d_out, int out_size, void* d_ws, size_t ws_size,
                              hipStream_t stream) {
  const int*   q     = (const int*)  d_in[0];
  const int*   r     = (const int*)  d_in[1];
  const float* k_emb = (const float*)d_in[2];
  const float* Mk    = (const float*)d_in[3];
  const float* Mv0   = (const float*)d_in[4];
  const float* f_W   = (const float*)d_in[5];
  const float* f_b   = (const float*)d_in[6];
  const float* a_W   = (const float*)d_in[7];
  const float* a_b   = (const float*)d_in[8];
  const float* e_W   = (const float*)d_in[9];
  const float* e_b   = (const float*)d_in[10];
  const float* add_W = (const float*)d_in[11];
  const float* add_b = (const float*)d_in[12];
  const float* Wih   = (const float*)d_in[13];
  const float* Whh   = (const float*)d_in[14];
  const float* bih   = (const float*)d_in[15];
  const float* bhh   = (const float*)d_in[16];
  const float* p_W   = (const float*)d_in[17];
  const float* p_b   = (const float*)d_in[18];
  float* out = (float*)d_out;

  char* ws = (char*)d_ws;
  size_t off = 0;
  auto alloc = [&](size_t bytes) -> char* {
    char* p = ws + off;
    off += (bytes + 255) & ~(size_t)255;
    return p;
  };
  float* wAll  = (float*)alloc((size_t)BB*TT*MM*4);
  float* fpre  = (float*)alloc((size_t)BB*TT*DD*4);
  float* ypre  = (float*)alloc((size_t)BB*TT*DD*4);
  float* fAll  = (float*)alloc((size_t)BB*TT*DD*4);
  float* eapre = (float*)alloc((size_t)BB*TT*256*4);
  float* Hh    = (float*)alloc((size_t)BB*TT*DD*4);
  float* Ch    = (float*)alloc((size_t)BB*TT*DD*4);
  ull*   keyLo = (ull*)  alloc((size_t)BB*TT*8);
  ull*   keyHi = (ull*)  alloc((size_t)BB*TT*8);
  int*   prevA = (int*)  alloc((size_t)BB*TT*4);
  float* Ge    = (float*)alloc((size_t)DD*DD*4);
  float* Ga    = (float*)alloc((size_t)DD*DD*4);
  float* Wih4  = (float*)alloc((size_t)512*DD*4);
  int*   prog  = (int*)  alloc(256);
  (void)ws_size; (void)in_sizes; (void)n_in; (void)out_size;

  hipMemsetAsync(prog, 0, 32*sizeof(int), stream);   // reset pipeline flags
  kPre  <<<dim3(16, 32), 256, 0, stream>>>(q, r, k_emb, Mk, f_W, f_b, a_W, a_b,
                                           wAll, keyLo, keyHi, fpre, ypre);
  kWW   <<<128, 128, 0, stream>>>(e_W, add_W, a_W, Ge, Ga);
  kEA   <<<dim3(4, 512), 256, 0, stream>>>(ypre, e_W, add_W, e_b, add_b, eapre);
  kWih4 <<<256, 256, 0, stream>>>(Wih, Wih4);
  kMatch<<<32, 512, 0, stream>>>(keyLo, keyHi, prevA);
  kFused<<<64, 512, 0, stream>>>(wAll, fpre, eapre, f_W, Ge, Ga, Mv0, fAll,
                                 Wih4, bih, bhh, prevA, Whh, Hh, Ch, prog);
  kOut  <<<(BB*TT)/16, 256, 0, stream>>>(Hh, p_W, p_b, out);
}

// Round 10
// 784.715 us; speedup vs baseline: 11.8410x; 11.8410x over previous
//
#include <hip/hip_runtime.h>
#include <cstdint>
#include <cstddef>

// Problem constants
#define NUM_C 4096
#define BB 32
#define TT 512
#define DD 128
#define MM 50

using ull = unsigned long long;

__device__ __forceinline__ float sigmoidf_(float x){ return 1.0f/(1.0f + expf(-x)); }

// Fast transcendentals on the serial critical path: v_exp_f32 / v_rcp_f32
__device__ __forceinline__ float fexp2_(float x){ return __builtin_amdgcn_exp2f(x); }
__device__ __forceinline__ float frcp_(float x){ return __builtin_amdgcn_rcpf(x); }
__device__ __forceinline__ float fast_sig_(float x){
  return frcp_(1.0f + fexp2_(-1.44269504088896341f*x));
}
__device__ __forceinline__ float fast_tanh_(float x){
  float t = fexp2_(2.88539008177792681f*x);     // e^(2x)
  return 1.0f - 2.0f*frcp_(t + 1.0f);
}

// Quad reduction via DPP (VALU pipe, no LDS): sum over lanes {x, x^1, x^2, x^3}
__device__ __forceinline__ float quadSum_(float v){
  int t = __builtin_amdgcn_update_dpp(0, __float_as_int(v), 0xB1, 0xF, 0xF, true);
  v += __int_as_float(t);
  t = __builtin_amdgcn_update_dpp(0, __float_as_int(v), 0x4E, 0xF, 0xF, true);
  v += __int_as_float(t);
  return v;
}

// Relaxed barrier: LDS visibility only (no vmcnt/expcnt drain).
__device__ __forceinline__ void barL_(){
  asm volatile("s_waitcnt lgkmcnt(0)\n\ts_barrier" ::: "memory");
}
// Drain this thread's outstanding vector-memory ops (used before publishing
// a cross-block progress flag).
__device__ __forceinline__ void waitVM_(){
  asm volatile("s_waitcnt vmcnt(0)" ::: "memory");
}

// ---------------------------------------------------------------------------
// Kernel A: parallel precompute (unchanged).
// ---------------------------------------------------------------------------
__global__ __launch_bounds__(256) void kPre(
    const int* __restrict__ q, const int* __restrict__ r,
    const float* __restrict__ k_emb, const float* __restrict__ Mk,
    const float* __restrict__ f_W, const float* __restrict__ f_b,
    const float* __restrict__ a_W, const float* __restrict__ a_b,
    float* __restrict__ wAll, ull* __restrict__ keyLo, ull* __restrict__ keyHi,
    float* __restrict__ fpre, float* __restrict__ ypre)
{
  const int b = blockIdx.y, t0 = blockIdx.x * 32, tid = threadIdx.x;
  __shared__ __align__(16) float sK[32*129];
  __shared__ int sQ[32];
  __shared__ int sR[32];
  __shared__ union UU {
    struct { float sMk[MM*129]; double sZ[32*MM]; } p2;
    float sW2[128*65];
  } u;

  if (tid < 32){ sQ[tid] = q[b*TT + t0 + tid]; sR[tid] = r[b*TT + t0 + tid]; }
  __syncthreads();
  for (int i = tid; i < 32*128; i += 256){
    int tl = i >> 7, j = i & 127;
    sK[tl*129 + j] = k_emb[(size_t)sQ[tl]*DD + j];
  }
  for (int i = tid; i < MM*128; i += 256){
    int m = i >> 7, j = i & 127;
    u.p2.sMk[m*129 + j] = Mk[i];
  }
  __syncthreads();

  for (int idx = tid; idx < 32*MM; idx += 256){
    int tl = idx / MM, m = idx - tl*MM;
    double z = 0.0;
    for (int j = 0; j < DD; j++)
      z += (double)sK[tl*129 + j] * (double)u.p2.sMk[m*129 + j];
    u.p2.sZ[tl*MM + m] = z;
  }
  __syncthreads();

  {
    int tl = tid >> 3, l8 = tid & 7;
    double zmax = -1e300;
    for (int m = l8; m < MM; m += 8) zmax = fmax(zmax, u.p2.sZ[tl*MM + m]);
    for (int s = 1; s < 8; s <<= 1) zmax = fmax(zmax, __shfl_xor(zmax, s));
    double se = 0.0;
    for (int m = l8; m < MM; m += 8){
      double e = exp(u.p2.sZ[tl*MM + m] - zmax);
      u.p2.sZ[tl*MM + m] = e;
      se += e;
    }
    for (int s = 1; s < 8; s <<= 1) se += __shfl_xor(se, s);
    double inv = 1.0 / se;
    ull klo = 0, khi = 0;
    for (int m = l8; m < MM; m += 8){
      double w = u.p2.sZ[tl*MM + m] * inv;
      wAll[((size_t)(b*TT + t0 + tl))*MM + m] = (float)w;
      double tw = fmin((w - 0.075)/(0.088 - 0.075), (1.0 - w)/(1.0 - 0.088));
      tw = fmax(tw, 0.0);
      ull iv = (tw >= 0.6) ? 2ull : ((tw >= 0.1) ? 1ull : 0ull);
      if (m < 32) klo |= iv << (2*m); else khi |= iv << (2*(m-32));
    }
    for (int s = 1; s < 8; s <<= 1){ klo |= __shfl_xor(klo, s); khi |= __shfl_xor(khi, s); }
    if (l8 == 0){ keyLo[b*TT + t0 + tl] = klo; keyHi[b*TT + t0 + tl] = khi; }
  }

  {
    const int dq = tid & 31, tq = tid >> 5;
    float acc[4][4];
    #pragma unroll
    for (int a = 0; a < 4; a++){ acc[a][0]=0.f; acc[a][1]=0.f; acc[a][2]=0.f; acc[a][3]=0.f; }
    for (int jh = 0; jh < 2; jh++){
      __syncthreads();
      for (int i = tid; i < 128*64; i += 256){
        int dd = i >> 6, jj = i & 63;
        u.sW2[dd*65 + jj] = f_W[dd*256 + 128 + jh*64 + jj];
      }
      __syncthreads();
      for (int jj = 0; jj < 64; jj++){
        float kv[4], wv[4];
        #pragma unroll
        for (int a = 0; a < 4; a++) kv[a] = sK[(tq*4 + a)*129 + jh*64 + jj];
        #pragma unroll
        for (int c = 0; c < 4; c++) wv[c] = u.sW2[(dq*4 + c)*65 + jj];
        #pragma unroll
        for (int a = 0; a < 4; a++){
          acc[a][0] += kv[a]*wv[0]; acc[a][1] += kv[a]*wv[1];
          acc[a][2] += kv[a]*wv[2]; acc[a][3] += kv[a]*wv[3];
        }
      }
    }
    #pragma unroll
    for (int a = 0; a < 4; a++){
      int tl = tq*4 + a;
      #pragma unroll
      for (int c = 0; c < 4; c++){
        int d = dq*4 + c;
        fpre[((size_t)(b*TT + t0 + tl))*DD + d] = acc[a][c] + f_b[d];
      }
    }
  }

  for (int i = tid; i < 32*DD; i += 256){
    int tl = i >> 7, d = i & 127;
    ypre[((size_t)(b*TT + t0 + tl))*DD + d] =
        a_W[(size_t)d*(NUM_C + DD) + sQ[tl]] * (float)sR[tl] + a_b[d];
  }
}

// ---------------------------------------------------------------------------
// Kernel A2: exact match search (unchanged).
// ---------------------------------------------------------------------------
__global__ __launch_bounds__(512) void kMatch(
    const ull* __restrict__ keyLo, const ull* __restrict__ keyHi, int* __restrict__ prevA)
{
  const int b = blockIdx.x, i = threadIdx.x;
  __shared__ ull slo[TT];
  __shared__ ull shi[TT];
  slo[i] = keyLo[b*TT + i];
  shi[i] = keyHi[b*TT + i];
  __syncthreads();
  const ull mylo = slo[i], myhi = shi[i];
  int found = -1;
  for (int j = i - 1; j >= 0; j--){
    if (slo[j] == mylo && shi[j] == myhi){ found = j; break; }
  }
  prevA[b*TT + i] = found;
}

// ---------------------------------------------------------------------------
// Kernel W: one-time weight products (unchanged).
// ---------------------------------------------------------------------------
__global__ __launch_bounds__(128) void kWW(
    const float* __restrict__ e_W, const float* __restrict__ add_W,
    const float* __restrict__ a_W,
    float* __restrict__ Ge, float* __restrict__ Ga)
{
  const int d = blockIdx.x;    // 0..127
  const int k = threadIdx.x;   // 0..127
  __shared__ float se[128];
  __shared__ float sa[128];
  se[k] = e_W[(size_t)d*DD + k];
  sa[k] = add_W[(size_t)d*DD + k];
  __syncthreads();
  float ge = 0.f, ga = 0.f;
  for (int j = 0; j < DD; j++){
    float af = a_W[(size_t)j*(NUM_C + DD) + NUM_C + k];
    ge += se[j]*af;
    ga += sa[j]*af;
  }
  Ge[(size_t)d*DD + k] = ge;
  Ga[(size_t)d*DD + k] = ga;
}

// ---------------------------------------------------------------------------
// Kernel EA: eapre GEMM (unchanged).
// ---------------------------------------------------------------------------
__global__ __launch_bounds__(256) void kEA(
    const float* __restrict__ ypre, const float* __restrict__ e_W,
    const float* __restrict__ add_W, const float* __restrict__ e_b,
    const float* __restrict__ add_b, float* __restrict__ eapre)
{
  const int jt = blockIdx.x;   // 0..3  (64 output cols each)
  const int rt = blockIdx.y;   // 0..511 (32 rows each)
  const int tid = threadIdx.x;
  __shared__ float sW[64*129];
  __shared__ float sF[32*129];
  for (int i = tid; i < 64*128; i += 256){
    int jj = i >> 7, k = i & 127;
    int j = jt*64 + jj;
    sW[jj*129 + k] = (j < 128) ? e_W[(size_t)j*DD + k] : add_W[(size_t)(j-128)*DD + k];
  }
  for (int i = tid; i < 32*128; i += 256){
    int rr = i >> 7, k = i & 127;
    sF[rr*129 + k] = ypre[(size_t)(rt*32 + rr)*DD + k];
  }
  __syncthreads();
  const int jq = tid & 31, rq = tid >> 5;
  float acc[4][2];
  #pragma unroll
  for (int a = 0; a < 4; a++){ acc[a][0] = 0.f; acc[a][1] = 0.f; }
  for (int k = 0; k < 128; k++){
    float fv[4], wv[2];
    #pragma unroll
    for (int a = 0; a < 4; a++) fv[a] = sF[(rq*4 + a)*129 + k];
    wv[0] = sW[(jq*2 + 0)*129 + k];
    wv[1] = sW[(jq*2 + 1)*129 + k];
    #pragma unroll
    for (int a = 0; a < 4; a++){ acc[a][0] += fv[a]*wv[0]; acc[a][1] += fv[a]*wv[1]; }
  }
  #pragma unroll
  for (int a = 0; a < 4; a++){
    int rowi = rt*32 + rq*4 + a;
    #pragma unroll
    for (int c = 0; c < 2; c++){
      int j = jt*64 + jq*2 + c;
      float bj = (j < 128) ? e_b[j] : add_b[j - 128];
      eapre[(size_t)rowi*256 + j] = acc[a][c] + bj;
    }
  }
}

// ---------------------------------------------------------------------------
// Kernel W4: repack Wih into k-major float4 tiles (unchanged).
// ---------------------------------------------------------------------------
__global__ __launch_bounds__(256) void kWih4(
    const float* __restrict__ Wih, float* __restrict__ Wih4)
{
  int idx = blockIdx.x*256 + threadIdx.x;     // 0..65535
  int j = idx >> 7, k = idx & 127;
  Wih4[(size_t)(k >> 2)*2048 + j*4 + (k & 3)] = Wih[idx];
}

// ---------------------------------------------------------------------------
// Kernel F (R14): 3-role fused pipeline, chunk-granular flags.
//   Blocks  0..31: memory recurrence (R12 role, <=116 VGPR) -> fAll, prog[b]
//   Blocks 32..63: gates GEMM (R12's per-column GEMM, ~30 VGPR):
//                  wait prog[b] -> stage fAll chunk -> 8x512 GEMM ->
//                  agent-store gpre chunk -> drain -> prog[32+b]
//   Blocks 64..95: LSTM (R10 role): wait prog[32+b] -> stage gpre chunk to
//                  LDS -> 8 steps.
// Rationale: R13 proved in-thread GEMM/LSTM overlap spills (128-VGPR wall
// for 512-thread blocks). This overlaps them ACROSS CUs — each role keeps
// its verified register footprint. 96 blocks co-resident -> deadlock-free.
// ---------------------------------------------------------------------------
__global__ __launch_bounds__(512, 2) __attribute__((amdgpu_waves_per_eu(2, 2)))
void kFused(
    const float* __restrict__ wAll, const float* __restrict__ fpre,
    const float* __restrict__ eapre, const float* __restrict__ f_W,
    const float* __restrict__ Ge, const float* __restrict__ Ga,
    const float* __restrict__ Mv0, float* __restrict__ fAll,
    const float* __restrict__ Wih4, const float* __restrict__ bih,
    const float* __restrict__ bhh, const int* __restrict__ prevA,
    const float* __restrict__ Whh, float* __restrict__ Hh,
    float* __restrict__ Ch, float* __restrict__ gpre, int* __restrict__ prog)
{
  const int tid = threadIdx.x;
  const int b = blockIdx.x & 31;
  const size_t base = (size_t)b*TT;

  __shared__ __align__(16) union SU {
    struct {
      float bufR[144]; float bufF[144]; float sW9[9*52];
      float sF8[8*128]; float sEA8[8*256]; float fO8[8*128];
    } m;
    struct { float sFc[8*128]; } g;
    struct {
      float xh[2][144]; float gbuf[8*512]; int spv[TT];
      float hRing[8*128]; float cRing[8*128];
    } l;
  } su;

  if (blockIdx.x < 32){
    // ==================== memory-recurrence role (R12 verbatim) ============
    const int dd = tid >> 2, kc = tid & 3, m0 = kc*13;
    const int wslot = (dd >> 5)*36 + (dd & 31);

    float mv[13];
    #pragma unroll
    for (int i = 0; i < 13; i++){
      int m = m0 + i;
      mv[i] = (m < MM) ? Mv0[(size_t)m*DD + dd] : 0.f;
    }
    float wf[32], ge[32], ga[32];
    {
      const float4* p;
      p = reinterpret_cast<const float4*>(&f_W[dd*256 + kc*32]);
      #pragma unroll
      for (int i = 0; i < 8; i++){ float4 v = p[i]; wf[4*i]=v.x; wf[4*i+1]=v.y; wf[4*i+2]=v.z; wf[4*i+3]=v.w; }
      p = reinterpret_cast<const float4*>(&Ge[(size_t)dd*DD + kc*32]);
      #pragma unroll
      for (int i = 0; i < 8; i++){ float4 v = p[i]; ge[4*i]=v.x; ge[4*i+1]=v.y; ge[4*i+2]=v.z; ge[4*i+3]=v.w; }
      p = reinterpret_cast<const float4*>(&Ga[(size_t)dd*DD + kc*32]);
      #pragma unroll
      for (int i = 0; i < 8; i++){ float4 v = p[i]; ga[4*i]=v.x; ga[4*i+1]=v.y; ga[4*i+2]=v.z; ga[4*i+3]=v.w; }
    }

    const int rr0 = tid / 50, mm0 = tid - rr0*50;   // valid when tid < 450
    if (tid < 18){ int rr = tid >> 1; su.m.sW9[rr*52 + 50 + (tid & 1)] = 0.f; }

    float4 pF = {0.f,0.f,0.f,0.f}, pEA = {0.f,0.f,0.f,0.f};
    float pW = 0.f;
    if (tid < 256) pF = reinterpret_cast<const float4*>(&fpre[base*DD])[tid];
    pEA = reinterpret_cast<const float4*>(&eapre[base*256])[tid];
    if (tid < 450) pW = wAll[(base + rr0)*MM + mm0];

    float wreg[13];

    for (int ch = 0; ch < TT/8; ch++){
      const int t0 = ch*8;
      if (ch){
        if (tid < 256){
          float4 v = reinterpret_cast<const float4*>(su.m.fO8)[tid];
          float* dst = &fAll[(base + t0 - 8)*DD + tid*4];
          __hip_atomic_store(dst+0, v.x, __ATOMIC_RELAXED, __HIP_MEMORY_SCOPE_AGENT);
          __hip_atomic_store(dst+1, v.y, __ATOMIC_RELAXED, __HIP_MEMORY_SCOPE_AGENT);
          __hip_atomic_store(dst+2, v.z, __ATOMIC_RELAXED, __HIP_MEMORY_SCOPE_AGENT);
          __hip_atomic_store(dst+3, v.w, __ATOMIC_RELAXED, __HIP_MEMORY_SCOPE_AGENT);
        }
      }
      if (tid < 256) reinterpret_cast<float4*>(su.m.sF8)[tid] = pF;
      reinterpret_cast<float4*>(su.m.sEA8)[tid] = pEA;
      if (tid < 450) su.m.sW9[rr0*52 + mm0] = pW;
      if (ch && tid < 256) waitVM_();     // chunk stores complete before flag
      if (t0 + 8 < TT){
        if (tid < 256) pF = reinterpret_cast<const float4*>(&fpre[(base + t0 + 8)*DD])[tid];
        pEA = reinterpret_cast<const float4*>(&eapre[(base + t0 + 8)*256])[tid];
        if (tid < 450) pW = (t0 + 8 + rr0 < TT) ? wAll[(base + t0 + 8 + rr0)*MM + mm0] : 0.f;
      }
      barL_();   // R: chunk published (and all chunk stores drained)
      if (ch && tid == 0)
        __hip_atomic_store(&prog[b], ch, __ATOMIC_RELAXED, __HIP_MEMORY_SCOPE_AGENT);

      if (ch == 0){
        #pragma unroll
        for (int i = 0; i < 13; i++) wreg[i] = su.m.sW9[m0 + i];
        float r = 0.f;
        #pragma unroll
        for (int i = 0; i < 13; i++) r += wreg[i]*mv[i];
        r = quadSum_(r);
        if (kc == 0) su.m.bufR[wslot] = r;
        barL_();
      }

      #pragma unroll
      for (int tc = 0; tc < 8; tc++){
        float wn[13];
        #pragma unroll
        for (int i = 0; i < 13; i++) wn[i] = su.m.sW9[(tc+1)*52 + m0 + i];

        // ---- stage F: f = tanh(read @ f_Wr.T + fpre) ----
        {
          const float4* x4 = reinterpret_cast<const float4*>(&su.m.bufR[kc*36]);
          float a0=0.f,a1=0.f,a2=0.f,a3=0.f;
          #pragma unroll
          for (int i = 0; i < 8; i++){
            float4 xv = x4[i];
            a0 += xv.x*wf[4*i]; a1 += xv.y*wf[4*i+1]; a2 += xv.z*wf[4*i+2]; a3 += xv.w*wf[4*i+3];
          }
          float s = quadSum_((a0+a1)+(a2+a3));
          float fval = fast_tanh_(s + su.m.sF8[tc*128 + dd]);
          if (kc == 0){
            su.m.bufF[wslot] = fval;
            su.m.fO8[tc*128 + dd] = fval;
          }
        }
        barL_();   // B

        // ---- stage EA: e,a from f; mv update; read_{t+1} = wn . mv_new ----
        {
          const float4* x4 = reinterpret_cast<const float4*>(&su.m.bufF[kc*36]);
          float e0=0.f,e1=0.f,g0=0.f,g1=0.f;
          #pragma unroll
          for (int i = 0; i < 8; i++){
            float4 xv = x4[i];
            e0 += xv.x*ge[4*i];   e1 += xv.y*ge[4*i+1];
            e0 += xv.z*ge[4*i+2]; e1 += xv.w*ge[4*i+3];
            g0 += xv.x*ga[4*i];   g1 += xv.y*ga[4*i+1];
            g0 += xv.z*ga[4*i+2]; g1 += xv.w*ga[4*i+3];
          }
          float ep = quadSum_(e0 + e1);
          float ap = quadSum_(g0 + g1);
          float e_d = fast_sig_(ep + su.m.sEA8[tc*256 + dd]);
          float a_d = fast_tanh_(ap + su.m.sEA8[tc*256 + 128 + dd]);
          float rp0 = 0.f, rp1 = 0.f;
          #pragma unroll
          for (int i = 0; i < 13; i++){
            float t = __builtin_fmaf(-e_d, mv[i], a_d);
            mv[i] = __builtin_fmaf(wreg[i], t, mv[i]);
            if (i & 1) rp1 = __builtin_fmaf(wn[i], mv[i], rp1);
            else       rp0 = __builtin_fmaf(wn[i], mv[i], rp0);
          }
          float rd = quadSum_(rp0 + rp1);
          if (kc == 0) su.m.bufR[wslot] = rd;
        }
        #pragma unroll
        for (int i = 0; i < 13; i++) wreg[i] = wn[i];
        barL_();   // C
      }
    }

    // tail: store last chunk + final flag
    if (tid < 256){
      float4 v = reinterpret_cast<const float4*>(su.m.fO8)[tid];
      float* dst = &fAll[(base + TT - 8)*DD + tid*4];
      __hip_atomic_store(dst+0, v.x, __ATOMIC_RELAXED, __HIP_MEMORY_SCOPE_AGENT);
      __hip_atomic_store(dst+1, v.y, __ATOMIC_RELAXED, __HIP_MEMORY_SCOPE_AGENT);
      __hip_atomic_store(dst+2, v.z, __ATOMIC_RELAXED, __HIP_MEMORY_SCOPE_AGENT);
      __hip_atomic_store(dst+3, v.w, __ATOMIC_RELAXED, __HIP_MEMORY_SCOPE_AGENT);
      waitVM_();
    }
    __syncthreads();
    if (tid == 0)
      __hip_atomic_store(&prog[b], TT/8, __ATOMIC_RELAXED, __HIP_MEMORY_SCOPE_AGENT);

  } else if (blockIdx.x < 64){
    // ==================== gates-GEMM role (R12 consumer GEMM) ==============
    const float biasj = bih[tid] + bhh[tid];   // thread owns gate-column j = tid

    for (int ch = 0; ch < TT/8; ch++){
      const int t0 = ch*8;
      if (ch) __syncthreads();   // sFc reads from prev chunk done

      if (tid == 0){
        while (__hip_atomic_load(&prog[b], __ATOMIC_ACQUIRE, __HIP_MEMORY_SCOPE_AGENT) < ch + 1)
          __builtin_amdgcn_s_sleep(2);
      }
      __syncthreads();
      if (tid < 256){
        const float* src = &fAll[(base + t0)*DD + tid*4];
        float x0 = __hip_atomic_load(src+0, __ATOMIC_RELAXED, __HIP_MEMORY_SCOPE_AGENT);
        float x1 = __hip_atomic_load(src+1, __ATOMIC_RELAXED, __HIP_MEMORY_SCOPE_AGENT);
        float x2 = __hip_atomic_load(src+2, __ATOMIC_RELAXED, __HIP_MEMORY_SCOPE_AGENT);
        float x3 = __hip_atomic_load(src+3, __ATOMIC_RELAXED, __HIP_MEMORY_SCOPE_AGENT);
        su.g.sFc[tid*4+0] = x0; su.g.sFc[tid*4+1] = x1;
        su.g.sFc[tid*4+2] = x2; su.g.sFc[tid*4+3] = x3;
      }
      barL_();

      float acc[8];
      #pragma unroll
      for (int u = 0; u < 8; u++) acc[u] = 0.f;
      for (int k4 = 0; k4 < 32; k4++){
        float4 wv = reinterpret_cast<const float4*>(Wih4)[k4*512 + tid];
        #pragma unroll
        for (int u = 0; u < 8; u++){
          float4 fv = *reinterpret_cast<const float4*>(&su.g.sFc[u*128 + k4*4]);
          acc[u] += fv.x*wv.x; acc[u] += fv.y*wv.y;
          acc[u] += fv.z*wv.z; acc[u] += fv.w*wv.w;
        }
      }
      #pragma unroll
      for (int u = 0; u < 8; u++){
        float* dst = &gpre[(base + t0 + u)*512 + tid];
        __hip_atomic_store(dst, acc[u] + biasj, __ATOMIC_RELAXED, __HIP_MEMORY_SCOPE_AGENT);
      }
      waitVM_();
      __syncthreads();   // all threads' gpre stores drained
      if (tid == 0)
        __hip_atomic_store(&prog[32 + b], ch + 1, __ATOMIC_RELAXED, __HIP_MEMORY_SCOPE_AGENT);
    }

  } else {
    // ==================== LSTM role (R10 body, pipeline-fed) ===============
    const int jo = tid >> 2, kc = tid & 3;
    const int wslot = (jo >> 5)*36 + (jo & 31);

    float whh[4][32];
    #pragma unroll
    for (int g = 0; g < 4; g++){
      const float4* W4 = reinterpret_cast<const float4*>(&Whh[(size_t)(g*128 + jo)*128 + kc*32]);
      #pragma unroll
      for (int i = 0; i < 8; i++){
        float4 v = W4[i];
        whh[g][4*i] = v.x; whh[g][4*i+1] = v.y; whh[g][4*i+2] = v.z; whh[g][4*i+3] = v.w;
      }
    }

    su.l.spv[tid] = prevA[base + tid];
    if (tid < DD) su.l.xh[0][(tid >> 5)*36 + (tid & 31)] = 0.f;

    float cin_cur = 0.f;

    for (int ch = 0; ch < TT/8; ch++){
      const int t0 = ch*8;
      if (ch) __syncthreads();   // drains Hh/Ch stores; gbuf reads done

      if (tid == 0){
        while (__hip_atomic_load(&prog[32 + b], __ATOMIC_ACQUIRE, __HIP_MEMORY_SCOPE_AGENT) < ch + 1)
          __builtin_amdgcn_s_sleep(2);
      }
      __syncthreads();
      // stage gpre chunk (16 KB): thread -> 8 contiguous floats
      {
        const float* src = &gpre[(base + t0)*512 + tid*8];
        float x0 = __hip_atomic_load(src+0, __ATOMIC_RELAXED, __HIP_MEMORY_SCOPE_AGENT);
        float x1 = __hip_atomic_load(src+1, __ATOMIC_RELAXED, __HIP_MEMORY_SCOPE_AGENT);
        float x2 = __hip_atomic_load(src+2, __ATOMIC_RELAXED, __HIP_MEMORY_SCOPE_AGENT);
        float x3 = __hip_atomic_load(src+3, __ATOMIC_RELAXED, __HIP_MEMORY_SCOPE_AGENT);
        float x4 = __hip_atomic_load(src+4, __ATOMIC_RELAXED, __HIP_MEMORY_SCOPE_AGENT);
        float x5 = __hip_atomic_load(src+5, __ATOMIC_RELAXED, __HIP_MEMORY_SCOPE_AGENT);
        float x6 = __hip_atomic_load(src+6, __ATOMIC_RELAXED, __HIP_MEMORY_SCOPE_AGENT);
        float x7 = __hip_atomic_load(src+7, __ATOMIC_RELAXED, __HIP_MEMORY_SCOPE_AGENT);
        float* d = &su.l.gbuf[tid*8];
        d[0]=x0; d[1]=x1; d[2]=x2; d[3]=x3; d[4]=x4; d[5]=x5; d[6]=x6; d[7]=x7;
      }
      barL_();   // gbuf ready (+ xh ready for tc=0)

      #pragma unroll
      for (int tc = 0; tc < 8; tc++){
        const int t = t0 + tc, p = t & 1;
        if (tc) barL_();                 // xh[p] + ring ready

        int pv2 = -1; float preH = 0.f, preC = 0.f;
        if (t + 1 < TT){
          pv2 = su.l.spv[t + 1];
          if (pv2 >= 0 && pv2 < t){
            if (pv2 >= t0){              // in-chunk: LDS ring
              preH = su.l.hRing[(pv2 & 7)*128 + jo];
              preC = su.l.cRing[(pv2 & 7)*128 + jo];
            } else {                     // older chunk: global (same block wrote it)
              preH = Hh[(base + pv2)*DD + jo];
              preC = Ch[(base + pv2)*DD + jo];
            }
          }
        }

        float gp0 = su.l.gbuf[tc*512 + jo];
        float gp1 = su.l.gbuf[tc*512 + 128 + jo];
        float gp2 = su.l.gbuf[tc*512 + 256 + jo];
        float gp3 = su.l.gbuf[tc*512 + 384 + jo];

        float a0=0.f,a1=0.f,a2=0.f,a3=0.f;
        {
          const float4* x4 = reinterpret_cast<const float4*>(&su.l.xh[p][kc*36]);
          #pragma unroll
          for (int i = 0; i < 8; i++){
            float4 xv = x4[i];
            a0 += xv.x*whh[0][4*i]; a0 += xv.y*whh[0][4*i+1]; a0 += xv.z*whh[0][4*i+2]; a0 += xv.w*whh[0][4*i+3];
            a1 += xv.x*whh[1][4*i]; a1 += xv.y*whh[1][4*i+1]; a1 += xv.z*whh[1][4*i+2]; a1 += xv.w*whh[1][4*i+3];
            a2 += xv.x*whh[2][4*i]; a2 += xv.y*whh[2][4*i+1]; a2 += xv.z*whh[2][4*i+2]; a2 += xv.w*whh[2][4*i+3];
            a3 += xv.x*whh[3][4*i]; a3 += xv.y*whh[3][4*i+1]; a3 += xv.z*whh[3][4*i+2]; a3 += xv.w*whh[3][4*i+3];
          }
        }
        a0 = quadSum_(a0); a1 = quadSum_(a1); a2 = quadSum_(a2); a3 = quadSum_(a3);

        const float ig = gp0 + a0, fg = gp1 + a1, gg = gp2 + a2, og = gp3 + a3;
        const float cn = fast_sig_(fg)*cin_cur + fast_sig_(ig)*fast_tanh_(gg);
        const float hn = fast_sig_(og)*fast_tanh_(cn);

        if (kc == 0){
          Hh[(base + t)*DD + jo] = hn;
          Ch[(base + t)*DD + jo] = cn;
          su.l.hRing[(t & 7)*128 + jo] = hn;
          su.l.cRing[(t & 7)*128 + jo] = cn;
        }

        float hin_n, cin_n;
        if (pv2 < 0 || pv2 >= t){ hin_n = hn; cin_n = cn; }       // carry
        else                     { hin_n = preH; cin_n = preC; }   // skip
        if (kc == 0) su.l.xh[1 - p][wslot] = hin_n;
        cin_cur = cin_n;
      }
    }
  }
}

// ---------------------------------------------------------------------------
// Kernel E: output head (unchanged).
// ---------------------------------------------------------------------------
__global__ __launch_bounds__(256) void kOut(
    const float* __restrict__ Hh, const float* __restrict__ p_W,
    const float* __restrict__ p_b, float* __restrict__ out)
{
  const int row = blockIdx.x*16 + (threadIdx.x >> 4);
  const int l = threadIdx.x & 15;
  const float4* h4 = reinterpret_cast<const float4*>(&Hh[(size_t)row*DD + l*8]);
  const float4* w4 = reinterpret_cast<const float4*>(&p_W[l*8]);
  float4 ha = h4[0], hb = h4[1], wa = w4[0], wb = w4[1];
  float s = ha.x*wa.x + ha.y*wa.y + ha.z*wa.z + ha.w*wa.w
          + hb.x*wb.x + hb.y*wb.y + hb.z*wb.z + hb.w*wb.w;
  s += __shfl_xor(s, 1); s += __shfl_xor(s, 2);
  s += __shfl_xor(s, 4); s += __shfl_xor(s, 8);
  if (l == 0) out[row] = sigmoidf_(s + p_b[0]);
}

// ---------------------------------------------------------------------------
// Launch.
// ---------------------------------------------------------------------------
extern "C" void kernel_launch(void* const* d_in, const int* in_sizes, int n_in,
                              void* d_out, int out_size, void* d_ws, size_t ws_size,
                              hipStream_t stream) {
  const int*   q     = (const int*)  d_in[0];
  const int*   r     = (const int*)  d_in[1];
  const float* k_emb = (const float*)d_in[2];
  const float* Mk    = (const float*)d_in[3];
  const float* Mv0   = (const float*)d_in[4];
  const float* f_W   = (const float*)d_in[5];
  const float* f_b   = (const float*)d_in[6];
  const float* a_W   = (const float*)d_in[7];
  const float* a_b   = (const float*)d_in[8];
  const float* e_W   = (const float*)d_in[9];
  const float* e_b   = (const float*)d_in[10];
  const float* add_W = (const float*)d_in[11];
  const float* add_b = (const float*)d_in[12];
  const float* Wih   = (const float*)d_in[13];
  const float* Whh   = (const float*)d_in[14];
  const float* bih   = (const float*)d_in[15];
  const float* bhh   = (const float*)d_in[16];
  const float* p_W   = (const float*)d_in[17];
  const float* p_b   = (const float*)d_in[18];
  float* out = (float*)d_out;

  char* ws = (char*)d_ws;
  size_t off = 0;
  auto alloc = [&](size_t bytes) -> char* {
    char* p = ws + off;
    off += (bytes + 255) & ~(size_t)255;
    return p;
  };
  float* wAll  = (float*)alloc((size_t)BB*TT*MM*4);
  float* fpre  = (float*)alloc((size_t)BB*TT*DD*4);
  float* ypre  = (float*)alloc((size_t)BB*TT*DD*4);
  float* fAll  = (float*)alloc((size_t)BB*TT*DD*4);
  float* eapre = (float*)alloc((size_t)BB*TT*256*4);
  float* gpre  = (float*)alloc((size_t)BB*TT*512*4);
  float* Hh    = (float*)alloc((size_t)BB*TT*DD*4);
  float* Ch    = (float*)alloc((size_t)BB*TT*DD*4);
  ull*   keyLo = (ull*)  alloc((size_t)BB*TT*8);
  ull*   keyHi = (ull*)  alloc((size_t)BB*TT*8);
  int*   prevA = (int*)  alloc((size_t)BB*TT*4);
  float* Ge    = (float*)alloc((size_t)DD*DD*4);
  float* Ga    = (float*)alloc((size_t)DD*DD*4);
  float* Wih4  = (float*)alloc((size_t)512*DD*4);
  int*   prog  = (int*)  alloc(512);
  (void)ws_size; (void)in_sizes; (void)n_in; (void)out_size;

  hipMemsetAsync(prog, 0, 64*sizeof(int), stream);   // reset pipeline flags
  kPre  <<<dim3(16, 32), 256, 0, stream>>>(q, r, k_emb, Mk, f_W, f_b, a_W, a_b,
                                           wAll, keyLo, keyHi, fpre, ypre);
  kWW   <<<128, 128, 0, stream>>>(e_W, add_W, a_W, Ge, Ga);
  kEA   <<<dim3(4, 512), 256, 0, stream>>>(ypre, e_W, add_W, e_b, add_b, eapre);
  kWih4 <<<256, 256, 0, stream>>>(Wih, Wih4);
  kMatch<<<32, 512, 0, stream>>>(keyLo, keyHi, prevA);
  kFused<<<96, 512, 0, stream>>>(wAll, fpre, eapre, f_W, Ge, Ga, Mv0, fAll,
                                 Wih4, bih, bhh, prevA, Whh, Hh, Ch, gpre, prog);
  kOut  <<<(BB*TT)/16, 256, 0, stream>>>(Hh, p_W, p_b, out);
}

// Round 11
// 758.501 us; speedup vs baseline: 12.2502x; 1.0346x over previous
//
#include <hip/hip_runtime.h>
#include <cstdint>
#include <cstddef>

// Problem constants
#define NUM_C 4096
#define BB 32
#define TT 512
#define DD 128
#define MM 50

using ull = unsigned long long;

__device__ __forceinline__ float sigmoidf_(float x){ return 1.0f/(1.0f + expf(-x)); }

// Fast transcendentals on the serial critical path: v_exp_f32 / v_rcp_f32
__device__ __forceinline__ float fexp2_(float x){ return __builtin_amdgcn_exp2f(x); }
__device__ __forceinline__ float frcp_(float x){ return __builtin_amdgcn_rcpf(x); }
__device__ __forceinline__ float fast_sig_(float x){
  return frcp_(1.0f + fexp2_(-1.44269504088896341f*x));
}
__device__ __forceinline__ float fast_tanh_(float x){
  float t = fexp2_(2.88539008177792681f*x);     // e^(2x)
  return 1.0f - 2.0f*frcp_(t + 1.0f);
}

// Quad reduction via DPP (VALU pipe, no LDS): sum over lanes {x, x^1, x^2, x^3}
__device__ __forceinline__ float quadSum_(float v){
  int t = __builtin_amdgcn_update_dpp(0, __float_as_int(v), 0xB1, 0xF, 0xF, true);
  v += __int_as_float(t);
  t = __builtin_amdgcn_update_dpp(0, __float_as_int(v), 0x4E, 0xF, 0xF, true);
  v += __int_as_float(t);
  return v;
}

// Relaxed barrier: LDS visibility only (no vmcnt/expcnt drain).
__device__ __forceinline__ void barL_(){
  asm volatile("s_waitcnt lgkmcnt(0)\n\ts_barrier" ::: "memory");
}
// Drain this thread's outstanding vector-memory ops (used before publishing
// a cross-block progress flag).
__device__ __forceinline__ void waitVM_(){
  asm volatile("s_waitcnt vmcnt(0)" ::: "memory");
}

// ---------------------------------------------------------------------------
// Kernel A: parallel precompute (unchanged).
// ---------------------------------------------------------------------------
__global__ __launch_bounds__(256) void kPre(
    const int* __restrict__ q, const int* __restrict__ r,
    const float* __restrict__ k_emb, const float* __restrict__ Mk,
    const float* __restrict__ f_W, const float* __restrict__ f_b,
    const float* __restrict__ a_W, const float* __restrict__ a_b,
    float* __restrict__ wAll, ull* __restrict__ keyLo, ull* __restrict__ keyHi,
    float* __restrict__ fpre, float* __restrict__ ypre)
{
  const int b = blockIdx.y, t0 = blockIdx.x * 32, tid = threadIdx.x;
  __shared__ __align__(16) float sK[32*129];
  __shared__ int sQ[32];
  __shared__ int sR[32];
  __shared__ union UU {
    struct { float sMk[MM*129]; double sZ[32*MM]; } p2;
    float sW2[128*65];
  } u;

  if (tid < 32){ sQ[tid] = q[b*TT + t0 + tid]; sR[tid] = r[b*TT + t0 + tid]; }
  __syncthreads();
  for (int i = tid; i < 32*128; i += 256){
    int tl = i >> 7, j = i & 127;
    sK[tl*129 + j] = k_emb[(size_t)sQ[tl]*DD + j];
  }
  for (int i = tid; i < MM*128; i += 256){
    int m = i >> 7, j = i & 127;
    u.p2.sMk[m*129 + j] = Mk[i];
  }
  __syncthreads();

  for (int idx = tid; idx < 32*MM; idx += 256){
    int tl = idx / MM, m = idx - tl*MM;
    double z = 0.0;
    for (int j = 0; j < DD; j++)
      z += (double)sK[tl*129 + j] * (double)u.p2.sMk[m*129 + j];
    u.p2.sZ[tl*MM + m] = z;
  }
  __syncthreads();

  {
    int tl = tid >> 3, l8 = tid & 7;
    double zmax = -1e300;
    for (int m = l8; m < MM; m += 8) zmax = fmax(zmax, u.p2.sZ[tl*MM + m]);
    for (int s = 1; s < 8; s <<= 1) zmax = fmax(zmax, __shfl_xor(zmax, s));
    double se = 0.0;
    for (int m = l8; m < MM; m += 8){
      double e = exp(u.p2.sZ[tl*MM + m] - zmax);
      u.p2.sZ[tl*MM + m] = e;
      se += e;
    }
    for (int s = 1; s < 8; s <<= 1) se += __shfl_xor(se, s);
    double inv = 1.0 / se;
    ull klo = 0, khi = 0;
    for (int m = l8; m < MM; m += 8){
      double w = u.p2.sZ[tl*MM + m] * inv;
      wAll[((size_t)(b*TT + t0 + tl))*MM + m] = (float)w;
      double tw = fmin((w - 0.075)/(0.088 - 0.075), (1.0 - w)/(1.0 - 0.088));
      tw = fmax(tw, 0.0);
      ull iv = (tw >= 0.6) ? 2ull : ((tw >= 0.1) ? 1ull : 0ull);
      if (m < 32) klo |= iv << (2*m); else khi |= iv << (2*(m-32));
    }
    for (int s = 1; s < 8; s <<= 1){ klo |= __shfl_xor(klo, s); khi |= __shfl_xor(khi, s); }
    if (l8 == 0){ keyLo[b*TT + t0 + tl] = klo; keyHi[b*TT + t0 + tl] = khi; }
  }

  {
    const int dq = tid & 31, tq = tid >> 5;
    float acc[4][4];
    #pragma unroll
    for (int a = 0; a < 4; a++){ acc[a][0]=0.f; acc[a][1]=0.f; acc[a][2]=0.f; acc[a][3]=0.f; }
    for (int jh = 0; jh < 2; jh++){
      __syncthreads();
      for (int i = tid; i < 128*64; i += 256){
        int dd = i >> 6, jj = i & 63;
        u.sW2[dd*65 + jj] = f_W[dd*256 + 128 + jh*64 + jj];
      }
      __syncthreads();
      for (int jj = 0; jj < 64; jj++){
        float kv[4], wv[4];
        #pragma unroll
        for (int a = 0; a < 4; a++) kv[a] = sK[(tq*4 + a)*129 + jh*64 + jj];
        #pragma unroll
        for (int c = 0; c < 4; c++) wv[c] = u.sW2[(dq*4 + c)*65 + jj];
        #pragma unroll
        for (int a = 0; a < 4; a++){
          acc[a][0] += kv[a]*wv[0]; acc[a][1] += kv[a]*wv[1];
          acc[a][2] += kv[a]*wv[2]; acc[a][3] += kv[a]*wv[3];
        }
      }
    }
    #pragma unroll
    for (int a = 0; a < 4; a++){
      int tl = tq*4 + a;
      #pragma unroll
      for (int c = 0; c < 4; c++){
        int d = dq*4 + c;
        fpre[((size_t)(b*TT + t0 + tl))*DD + d] = acc[a][c] + f_b[d];
      }
    }
  }

  for (int i = tid; i < 32*DD; i += 256){
    int tl = i >> 7, d = i & 127;
    ypre[((size_t)(b*TT + t0 + tl))*DD + d] =
        a_W[(size_t)d*(NUM_C + DD) + sQ[tl]] * (float)sR[tl] + a_b[d];
  }
}

// ---------------------------------------------------------------------------
// Kernel I: one-time weight prep — merges kWW (blocks 0..127) and the Wih
// repack (blocks 128..383). Bodies identical to R14's kWW / kWih4.
// ---------------------------------------------------------------------------
__global__ __launch_bounds__(256) void kInit(
    const float* __restrict__ e_W, const float* __restrict__ add_W,
    const float* __restrict__ a_W,
    float* __restrict__ Ge, float* __restrict__ Ga,
    const float* __restrict__ Wih, float* __restrict__ Wih4)
{
  const int bx = blockIdx.x, tid = threadIdx.x;
  if (bx < 128){
    __shared__ float se[128];
    __shared__ float sa[128];
    const int d = bx;
    if (tid < 128){
      se[tid] = e_W[(size_t)d*DD + tid];
      sa[tid] = add_W[(size_t)d*DD + tid];
    }
    __syncthreads();
    if (tid < 128){
      const int k = tid;
      float ge = 0.f, ga = 0.f;
      for (int j = 0; j < DD; j++){
        float af = a_W[(size_t)j*(NUM_C + DD) + NUM_C + k];
        ge += se[j]*af;
        ga += sa[j]*af;
      }
      Ge[(size_t)d*DD + k] = ge;
      Ga[(size_t)d*DD + k] = ga;
    }
  } else {
    int idx = (bx - 128)*256 + tid;     // 0..65535
    int j = idx >> 7, k = idx & 127;
    Wih4[(size_t)(k >> 2)*2048 + j*4 + (k & 3)] = Wih[idx];
  }
}

// ---------------------------------------------------------------------------
// Kernel EA: eapre GEMM (unchanged).
// ---------------------------------------------------------------------------
__global__ __launch_bounds__(256) void kEA(
    const float* __restrict__ ypre, const float* __restrict__ e_W,
    const float* __restrict__ add_W, const float* __restrict__ e_b,
    const float* __restrict__ add_b, float* __restrict__ eapre)
{
  const int jt = blockIdx.x;   // 0..3  (64 output cols each)
  const int rt = blockIdx.y;   // 0..511 (32 rows each)
  const int tid = threadIdx.x;
  __shared__ float sW[64*129];
  __shared__ float sF[32*129];
  for (int i = tid; i < 64*128; i += 256){
    int jj = i >> 7, k = i & 127;
    int j = jt*64 + jj;
    sW[jj*129 + k] = (j < 128) ? e_W[(size_t)j*DD + k] : add_W[(size_t)(j-128)*DD + k];
  }
  for (int i = tid; i < 32*128; i += 256){
    int rr = i >> 7, k = i & 127;
    sF[rr*129 + k] = ypre[(size_t)(rt*32 + rr)*DD + k];
  }
  __syncthreads();
  const int jq = tid & 31, rq = tid >> 5;
  float acc[4][2];
  #pragma unroll
  for (int a = 0; a < 4; a++){ acc[a][0] = 0.f; acc[a][1] = 0.f; }
  for (int k = 0; k < 128; k++){
    float fv[4], wv[2];
    #pragma unroll
    for (int a = 0; a < 4; a++) fv[a] = sF[(rq*4 + a)*129 + k];
    wv[0] = sW[(jq*2 + 0)*129 + k];
    wv[1] = sW[(jq*2 + 1)*129 + k];
    #pragma unroll
    for (int a = 0; a < 4; a++){ acc[a][0] += fv[a]*wv[0]; acc[a][1] += fv[a]*wv[1]; }
  }
  #pragma unroll
  for (int a = 0; a < 4; a++){
    int rowi = rt*32 + rq*4 + a;
    #pragma unroll
    for (int c = 0; c < 2; c++){
      int j = jt*64 + jq*2 + c;
      float bj = (j < 128) ? e_b[j] : add_b[j - 128];
      eapre[(size_t)rowi*256 + j] = acc[a][c] + bj;
    }
  }
}

// ---------------------------------------------------------------------------
// Kernel F (R15): 3-role fused pipeline.
//   Blocks  0..31: memory recurrence (R14 verbatim) -> fAll, prog[b]
//   Blocks 32..63: gates GEMM; PREPHASE = kMatch (key scan -> prevA, agent
//                  stores drained before prog2). Then per chunk: spin ->
//                  sync -> stage -> barL -> GEMM -> store -> drain -> sync
//                  -> flag (3 barriers/chunk, was 4).
//   Blocks 64..95: LSTM; spv loaded after first flag; 9 barriers/chunk
//                  (was 11); TAIL = kOut for this batch (own-block Hh).
// ---------------------------------------------------------------------------
__global__ __launch_bounds__(512, 2) __attribute__((amdgpu_waves_per_eu(2, 2)))
void kFused(
    const float* __restrict__ wAll, const float* __restrict__ fpre,
    const float* __restrict__ eapre, const float* __restrict__ f_W,
    const float* __restrict__ Ge, const float* __restrict__ Ga,
    const float* __restrict__ Mv0, float* __restrict__ fAll,
    const float* __restrict__ Wih4, const float* __restrict__ bih,
    const float* __restrict__ bhh, const ull* __restrict__ keyLo,
    const ull* __restrict__ keyHi, int* __restrict__ prevA,
    const float* __restrict__ Whh, float* __restrict__ Hh,
    float* __restrict__ Ch, float* __restrict__ gpre,
    const float* __restrict__ p_W, const float* __restrict__ p_b,
    float* __restrict__ out, int* __restrict__ prog)
{
  const int tid = threadIdx.x;
  const int b = blockIdx.x & 31;
  const size_t base = (size_t)b*TT;

  __shared__ __align__(16) union SU {
    struct {
      float bufR[144]; float bufF[144]; float sW9[9*52];
      float sF8[8*128]; float sEA8[8*256]; float fO8[8*128];
    } m;
    struct { float sFc[8*128]; ull slo[TT]; ull shi[TT]; } g;
    struct {
      float xh[2][144]; float gbuf[8*512]; int spv[TT];
      float hRing[8*128]; float cRing[8*128]; float pw[DD];
    } l;
  } su;

  if (blockIdx.x < 32){
    // ==================== memory-recurrence role (R14 verbatim) ============
    const int dd = tid >> 2, kc = tid & 3, m0 = kc*13;
    const int wslot = (dd >> 5)*36 + (dd & 31);

    float mv[13];
    #pragma unroll
    for (int i = 0; i < 13; i++){
      int m = m0 + i;
      mv[i] = (m < MM) ? Mv0[(size_t)m*DD + dd] : 0.f;
    }
    float wf[32], ge[32], ga[32];
    {
      const float4* p;
      p = reinterpret_cast<const float4*>(&f_W[dd*256 + kc*32]);
      #pragma unroll
      for (int i = 0; i < 8; i++){ float4 v = p[i]; wf[4*i]=v.x; wf[4*i+1]=v.y; wf[4*i+2]=v.z; wf[4*i+3]=v.w; }
      p = reinterpret_cast<const float4*>(&Ge[(size_t)dd*DD + kc*32]);
      #pragma unroll
      for (int i = 0; i < 8; i++){ float4 v = p[i]; ge[4*i]=v.x; ge[4*i+1]=v.y; ge[4*i+2]=v.z; ge[4*i+3]=v.w; }
      p = reinterpret_cast<const float4*>(&Ga[(size_t)dd*DD + kc*32]);
      #pragma unroll
      for (int i = 0; i < 8; i++){ float4 v = p[i]; ga[4*i]=v.x; ga[4*i+1]=v.y; ga[4*i+2]=v.z; ga[4*i+3]=v.w; }
    }

    const int rr0 = tid / 50, mm0 = tid - rr0*50;   // valid when tid < 450
    if (tid < 18){ int rr = tid >> 1; su.m.sW9[rr*52 + 50 + (tid & 1)] = 0.f; }

    float4 pF = {0.f,0.f,0.f,0.f}, pEA = {0.f,0.f,0.f,0.f};
    float pW = 0.f;
    if (tid < 256) pF = reinterpret_cast<const float4*>(&fpre[base*DD])[tid];
    pEA = reinterpret_cast<const float4*>(&eapre[base*256])[tid];
    if (tid < 450) pW = wAll[(base + rr0)*MM + mm0];

    float wreg[13];

    for (int ch = 0; ch < TT/8; ch++){
      const int t0 = ch*8;
      if (ch){
        if (tid < 256){
          float4 v = reinterpret_cast<const float4*>(su.m.fO8)[tid];
          float* dst = &fAll[(base + t0 - 8)*DD + tid*4];
          __hip_atomic_store(dst+0, v.x, __ATOMIC_RELAXED, __HIP_MEMORY_SCOPE_AGENT);
          __hip_atomic_store(dst+1, v.y, __ATOMIC_RELAXED, __HIP_MEMORY_SCOPE_AGENT);
          __hip_atomic_store(dst+2, v.z, __ATOMIC_RELAXED, __HIP_MEMORY_SCOPE_AGENT);
          __hip_atomic_store(dst+3, v.w, __ATOMIC_RELAXED, __HIP_MEMORY_SCOPE_AGENT);
        }
      }
      if (tid < 256) reinterpret_cast<float4*>(su.m.sF8)[tid] = pF;
      reinterpret_cast<float4*>(su.m.sEA8)[tid] = pEA;
      if (tid < 450) su.m.sW9[rr0*52 + mm0] = pW;
      if (ch && tid < 256) waitVM_();     // chunk stores complete before flag
      if (t0 + 8 < TT){
        if (tid < 256) pF = reinterpret_cast<const float4*>(&fpre[(base + t0 + 8)*DD])[tid];
        pEA = reinterpret_cast<const float4*>(&eapre[(base + t0 + 8)*256])[tid];
        if (tid < 450) pW = (t0 + 8 + rr0 < TT) ? wAll[(base + t0 + 8 + rr0)*MM + mm0] : 0.f;
      }
      barL_();   // R: chunk published (and all chunk stores drained)
      if (ch && tid == 0)
        __hip_atomic_store(&prog[b], ch, __ATOMIC_RELAXED, __HIP_MEMORY_SCOPE_AGENT);

      if (ch == 0){
        #pragma unroll
        for (int i = 0; i < 13; i++) wreg[i] = su.m.sW9[m0 + i];
        float r = 0.f;
        #pragma unroll
        for (int i = 0; i < 13; i++) r += wreg[i]*mv[i];
        r = quadSum_(r);
        if (kc == 0) su.m.bufR[wslot] = r;
        barL_();
      }

      #pragma unroll
      for (int tc = 0; tc < 8; tc++){
        float wn[13];
        #pragma unroll
        for (int i = 0; i < 13; i++) wn[i] = su.m.sW9[(tc+1)*52 + m0 + i];

        // ---- stage F: f = tanh(read @ f_Wr.T + fpre) ----
        {
          const float4* x4 = reinterpret_cast<const float4*>(&su.m.bufR[kc*36]);
          float a0=0.f,a1=0.f,a2=0.f,a3=0.f;
          #pragma unroll
          for (int i = 0; i < 8; i++){
            float4 xv = x4[i];
            a0 += xv.x*wf[4*i]; a1 += xv.y*wf[4*i+1]; a2 += xv.z*wf[4*i+2]; a3 += xv.w*wf[4*i+3];
          }
          float s = quadSum_((a0+a1)+(a2+a3));
          float fval = fast_tanh_(s + su.m.sF8[tc*128 + dd]);
          if (kc == 0){
            su.m.bufF[wslot] = fval;
            su.m.fO8[tc*128 + dd] = fval;
          }
        }
        barL_();   // B

        // ---- stage EA: e,a from f; mv update; read_{t+1} = wn . mv_new ----
        {
          const float4* x4 = reinterpret_cast<const float4*>(&su.m.bufF[kc*36]);
          float e0=0.f,e1=0.f,g0=0.f,g1=0.f;
          #pragma unroll
          for (int i = 0; i < 8; i++){
            float4 xv = x4[i];
            e0 += xv.x*ge[4*i];   e1 += xv.y*ge[4*i+1];
            e0 += xv.z*ge[4*i+2]; e1 += xv.w*ge[4*i+3];
            g0 += xv.x*ga[4*i];   g1 += xv.y*ga[4*i+1];
            g0 += xv.z*ga[4*i+2]; g1 += xv.w*ga[4*i+3];
          }
          float ep = quadSum_(e0 + e1);
          float ap = quadSum_(g0 + g1);
          float e_d = fast_sig_(ep + su.m.sEA8[tc*256 + dd]);
          float a_d = fast_tanh_(ap + su.m.sEA8[tc*256 + 128 + dd]);
          float rp0 = 0.f, rp1 = 0.f;
          #pragma unroll
          for (int i = 0; i < 13; i++){
            float t = __builtin_fmaf(-e_d, mv[i], a_d);
            mv[i] = __builtin_fmaf(wreg[i], t, mv[i]);
            if (i & 1) rp1 = __builtin_fmaf(wn[i], mv[i], rp1);
            else       rp0 = __builtin_fmaf(wn[i], mv[i], rp0);
          }
          float rd = quadSum_(rp0 + rp1);
          if (kc == 0) su.m.bufR[wslot] = rd;
        }
        #pragma unroll
        for (int i = 0; i < 13; i++) wreg[i] = wn[i];
        barL_();   // C
      }
    }

    // tail: store last chunk + final flag
    if (tid < 256){
      float4 v = reinterpret_cast<const float4*>(su.m.fO8)[tid];
      float* dst = &fAll[(base + TT - 8)*DD + tid*4];
      __hip_atomic_store(dst+0, v.x, __ATOMIC_RELAXED, __HIP_MEMORY_SCOPE_AGENT);
      __hip_atomic_store(dst+1, v.y, __ATOMIC_RELAXED, __HIP_MEMORY_SCOPE_AGENT);
      __hip_atomic_store(dst+2, v.z, __ATOMIC_RELAXED, __HIP_MEMORY_SCOPE_AGENT);
      __hip_atomic_store(dst+3, v.w, __ATOMIC_RELAXED, __HIP_MEMORY_SCOPE_AGENT);
      waitVM_();
    }
    __syncthreads();
    if (tid == 0)
      __hip_atomic_store(&prog[b], TT/8, __ATOMIC_RELAXED, __HIP_MEMORY_SCOPE_AGENT);

  } else if (blockIdx.x < 64){
    // ==================== gates-GEMM role (+ kMatch prephase) ==============
    const float biasj = bih[tid] + bhh[tid];   // thread owns gate-column j = tid

    // --- prephase: exact-match key scan for batch b (old kMatch body) ---
    {
      su.g.slo[tid] = keyLo[base + tid];
      su.g.shi[tid] = keyHi[base + tid];
      barL_();
      const ull mylo = su.g.slo[tid], myhi = su.g.shi[tid];
      int found = -1;
      for (int j = tid - 1; j >= 0; j--){
        if (su.g.slo[j] == mylo && su.g.shi[j] == myhi){ found = j; break; }
      }
      __hip_atomic_store(&prevA[base + tid], found, __ATOMIC_RELAXED, __HIP_MEMORY_SCOPE_AGENT);
      waitVM_();
      // prevA drained before this block's first prog2 store (below) -> the
      // LSTM role (which waits on prog2 >= 1) sees valid prevA.
    }

    for (int ch = 0; ch < TT/8; ch++){
      const int t0 = ch*8;
      if (tid == 0){
        while (__hip_atomic_load(&prog[b], __ATOMIC_ACQUIRE, __HIP_MEMORY_SCOPE_AGENT) < ch + 1)
          __builtin_amdgcn_s_sleep(2);
      }
      __syncthreads();   // A: join spin; prev chunk's sFc reads/stores done
      if (tid < 256){
        const float* src = &fAll[(base + t0)*DD + tid*4];
        float x0 = __hip_atomic_load(src+0, __ATOMIC_RELAXED, __HIP_MEMORY_SCOPE_AGENT);
        float x1 = __hip_atomic_load(src+1, __ATOMIC_RELAXED, __HIP_MEMORY_SCOPE_AGENT);
        float x2 = __hip_atomic_load(src+2, __ATOMIC_RELAXED, __HIP_MEMORY_SCOPE_AGENT);
        float x3 = __hip_atomic_load(src+3, __ATOMIC_RELAXED, __HIP_MEMORY_SCOPE_AGENT);
        su.g.sFc[tid*4+0] = x0; su.g.sFc[tid*4+1] = x1;
        su.g.sFc[tid*4+2] = x2; su.g.sFc[tid*4+3] = x3;
      }
      barL_();           // B: sFc published

      float acc[8];
      #pragma unroll
      for (int u = 0; u < 8; u++) acc[u] = 0.f;
      for (int k4 = 0; k4 < 32; k4++){
        float4 wv = reinterpret_cast<const float4*>(Wih4)[k4*512 + tid];
        #pragma unroll
        for (int u = 0; u < 8; u++){
          float4 fv = *reinterpret_cast<const float4*>(&su.g.sFc[u*128 + k4*4]);
          acc[u] += fv.x*wv.x; acc[u] += fv.y*wv.y;
          acc[u] += fv.z*wv.z; acc[u] += fv.w*wv.w;
        }
      }
      #pragma unroll
      for (int u = 0; u < 8; u++){
        float* dst = &gpre[(base + t0 + u)*512 + tid];
        __hip_atomic_store(dst, acc[u] + biasj, __ATOMIC_RELAXED, __HIP_MEMORY_SCOPE_AGENT);
      }
      waitVM_();
      __syncthreads();   // C: all threads' gpre stores drained
      if (tid == 0)
        __hip_atomic_store(&prog[32 + b], ch + 1, __ATOMIC_RELAXED, __HIP_MEMORY_SCOPE_AGENT);
    }

  } else {
    // ==================== LSTM role (+ kOut tail) ==========================
    const int jo = tid >> 2, kc = tid & 3;
    const int wslot = (jo >> 5)*36 + (jo & 31);

    float whh[4][32];
    #pragma unroll
    for (int g = 0; g < 4; g++){
      const float4* W4 = reinterpret_cast<const float4*>(&Whh[(size_t)(g*128 + jo)*128 + kc*32]);
      #pragma unroll
      for (int i = 0; i < 8; i++){
        float4 v = W4[i];
        whh[g][4*i] = v.x; whh[g][4*i+1] = v.y; whh[g][4*i+2] = v.z; whh[g][4*i+3] = v.w;
      }
    }

    float cin_cur = 0.f;

    for (int ch = 0; ch < TT/8; ch++){
      const int t0 = ch*8;
      if (tid == 0){
        while (__hip_atomic_load(&prog[32 + b], __ATOMIC_ACQUIRE, __HIP_MEMORY_SCOPE_AGENT) < ch + 1)
          __builtin_amdgcn_s_sleep(2);
      }
      __syncthreads();   // A: join spin; prev gbuf reads + Hh/Ch stores done
      if (ch == 0){
        // spv valid once prog2 >= 1 (GEMM role drains prevA before flag 1)
        su.l.spv[tid] = __hip_atomic_load(&prevA[base + tid], __ATOMIC_RELAXED, __HIP_MEMORY_SCOPE_AGENT);
        if (tid < DD) su.l.xh[0][(tid >> 5)*36 + (tid & 31)] = 0.f;
      }
      // stage gpre chunk (16 KB): thread -> 8 contiguous floats
      {
        const float* src = &gpre[(base + t0)*512 + tid*8];
        float x0 = __hip_atomic_load(src+0, __ATOMIC_RELAXED, __HIP_MEMORY_SCOPE_AGENT);
        float x1 = __hip_atomic_load(src+1, __ATOMIC_RELAXED, __HIP_MEMORY_SCOPE_AGENT);
        float x2 = __hip_atomic_load(src+2, __ATOMIC_RELAXED, __HIP_MEMORY_SCOPE_AGENT);
        float x3 = __hip_atomic_load(src+3, __ATOMIC_RELAXED, __HIP_MEMORY_SCOPE_AGENT);
        float x4 = __hip_atomic_load(src+4, __ATOMIC_RELAXED, __HIP_MEMORY_SCOPE_AGENT);
        float x5 = __hip_atomic_load(src+5, __ATOMIC_RELAXED, __HIP_MEMORY_SCOPE_AGENT);
        float x6 = __hip_atomic_load(src+6, __ATOMIC_RELAXED, __HIP_MEMORY_SCOPE_AGENT);
        float x7 = __hip_atomic_load(src+7, __ATOMIC_RELAXED, __HIP_MEMORY_SCOPE_AGENT);
        float* d = &su.l.gbuf[tid*8];
        d[0]=x0; d[1]=x1; d[2]=x2; d[3]=x3; d[4]=x4; d[5]=x5; d[6]=x6; d[7]=x7;
      }
      barL_();           // B: gbuf + (ch==0: spv/xh) ready

      #pragma unroll
      for (int tc = 0; tc < 8; tc++){
        const int t = t0 + tc, p = t & 1;
        if (tc) barL_();                 // xh[p] + ring ready

        int pv2 = -1; float preH = 0.f, preC = 0.f;
        if (t + 1 < TT){
          pv2 = su.l.spv[t + 1];
          if (pv2 >= 0 && pv2 < t){
            if (pv2 >= t0){              // in-chunk: LDS ring
              preH = su.l.hRing[(pv2 & 7)*128 + jo];
              preC = su.l.cRing[(pv2 & 7)*128 + jo];
            } else {                     // older chunk: global (same block wrote it)
              preH = Hh[(base + pv2)*DD + jo];
              preC = Ch[(base + pv2)*DD + jo];
            }
          }
        }

        float gp0 = su.l.gbuf[tc*512 + jo];
        float gp1 = su.l.gbuf[tc*512 + 128 + jo];
        float gp2 = su.l.gbuf[tc*512 + 256 + jo];
        float gp3 = su.l.gbuf[tc*512 + 384 + jo];

        float a0=0.f,a1=0.f,a2=0.f,a3=0.f;
        {
          const float4* x4 = reinterpret_cast<const float4*>(&su.l.xh[p][kc*36]);
          #pragma unroll
          for (int i = 0; i < 8; i++){
            float4 xv = x4[i];
            a0 += xv.x*whh[0][4*i]; a0 += xv.y*whh[0][4*i+1]; a0 += xv.z*whh[0][4*i+2]; a0 += xv.w*whh[0][4*i+3];
            a1 += xv.x*whh[1][4*i]; a1 += xv.y*whh[1][4*i+1]; a1 += xv.z*whh[1][4*i+2]; a1 += xv.w*whh[1][4*i+3];
            a2 += xv.x*whh[2][4*i]; a2 += xv.y*whh[2][4*i+1]; a2 += xv.z*whh[2][4*i+2]; a2 += xv.w*whh[2][4*i+3];
            a3 += xv.x*whh[3][4*i]; a3 += xv.y*whh[3][4*i+1]; a3 += xv.z*whh[3][4*i+2]; a3 += xv.w*whh[3][4*i+3];
          }
        }
        a0 = quadSum_(a0); a1 = quadSum_(a1); a2 = quadSum_(a2); a3 = quadSum_(a3);

        const float ig = gp0 + a0, fg = gp1 + a1, gg = gp2 + a2, og = gp3 + a3;
        const float cn = fast_sig_(fg)*cin_cur + fast_sig_(ig)*fast_tanh_(gg);
        const float hn = fast_sig_(og)*fast_tanh_(cn);

        if (kc == 0){
          Hh[(base + t)*DD + jo] = hn;
          Ch[(base + t)*DD + jo] = cn;
          su.l.hRing[(t & 7)*128 + jo] = hn;
          su.l.cRing[(t & 7)*128 + jo] = cn;
        }

        float hin_n, cin_n;
        if (pv2 < 0 || pv2 >= t){ hin_n = hn; cin_n = cn; }       // carry
        else                     { hin_n = preH; cin_n = preC; }   // skip
        if (kc == 0) su.l.xh[1 - p][wslot] = hin_n;
        cin_cur = cin_n;
      }
    }

    // ---- tail: output head for this batch (old kOut, bit-identical) ----
    __syncthreads();                       // drains this block's Hh stores
    if (tid < DD) su.l.pw[tid] = p_W[tid];
    barL_();
    {
      const int t = tid;                   // 512 rows, one per thread
      const float* hrow = &Hh[(base + t)*DD];
      float s = 0.f;
      #pragma unroll
      for (int k4 = 0; k4 < 32; k4++){
        float4 hv = *reinterpret_cast<const float4*>(&hrow[k4*4]);
        const float* wp = &su.l.pw[k4*4];
        s += hv.x*wp[0] + hv.y*wp[1] + hv.z*wp[2] + hv.w*wp[3];
      }
      out[base + t] = sigmoidf_(s + p_b[0]);
    }
  }
}

// ---------------------------------------------------------------------------
// Launch.
// ---------------------------------------------------------------------------
extern "C" void kernel_launch(void* const* d_in, const int* in_sizes, int n_in,
                              void* d_out, int out_size, void* d_ws, size_t ws_size,
                              hipStream_t stream) {
  const int*   q     = (const int*)  d_in[0];
  const int*   r     = (const int*)  d_in[1];
  const float* k_emb = (const float*)d_in[2];
  const float* Mk    = (const float*)d_in[3];
  const float* Mv0   = (const float*)d_in[4];
  const float* f_W   = (const float*)d_in[5];
  const float* f_b   = (const float*)d_in[6];
  const float* a_W   = (const float*)d_in[7];
  const float* a_b   = (const float*)d_in[8];
  const float* e_W   = (const float*)d_in[9];
  const float* e_b   = (const float*)d_in[10];
  const float* add_W = (const float*)d_in[11];
  const float* add_b = (const float*)d_in[12];
  const float* Wih   = (const float*)d_in[13];
  const float* Whh   = (const float*)d_in[14];
  const float* bih   = (const float*)d_in[15];
  const float* bhh   = (const float*)d_in[16];
  const float* p_W   = (const float*)d_in[17];
  const float* p_b   = (const float*)d_in[18];
  float* out = (float*)d_out;

  char* ws = (char*)d_ws;
  size_t off = 0;
  auto alloc = [&](size_t bytes) -> char* {
    char* p = ws + off;
    off += (bytes + 255) & ~(size_t)255;
    return p;
  };
  float* wAll  = (float*)alloc((size_t)BB*TT*MM*4);
  float* fpre  = (float*)alloc((size_t)BB*TT*DD*4);
  float* ypre  = (float*)alloc((size_t)BB*TT*DD*4);
  float* fAll  = (float*)alloc((size_t)BB*TT*DD*4);
  float* eapre = (float*)alloc((size_t)BB*TT*256*4);
  float* gpre  = (float*)alloc((size_t)BB*TT*512*4);
  float* Hh    = (float*)alloc((size_t)BB*TT*DD*4);
  float* Ch    = (float*)alloc((size_t)BB*TT*DD*4);
  ull*   keyLo = (ull*)  alloc((size_t)BB*TT*8);
  ull*   keyHi = (ull*)  alloc((size_t)BB*TT*8);
  int*   prevA = (int*)  alloc((size_t)BB*TT*4);
  float* Ge    = (float*)alloc((size_t)DD*DD*4);
  float* Ga    = (float*)alloc((size_t)DD*DD*4);
  float* Wih4  = (float*)alloc((size_t)512*DD*4);
  int*   prog  = (int*)  alloc(512);
  (void)ws_size; (void)in_sizes; (void)n_in; (void)out_size;

  hipMemsetAsync(prog, 0, 64*sizeof(int), stream);   // reset pipeline flags
  kPre  <<<dim3(16, 32), 256, 0, stream>>>(q, r, k_emb, Mk, f_W, f_b, a_W, a_b,
                                           wAll, keyLo, keyHi, fpre, ypre);
  kInit <<<384, 256, 0, stream>>>(e_W, add_W, a_W, Ge, Ga, Wih, Wih4);
  kEA   <<<dim3(4, 512), 256, 0, stream>>>(ypre, e_W, add_W, e_b, add_b, eapre);
  kFused<<<96, 512, 0, stream>>>(wAll, fpre, eapre, f_W, Ge, Ga, Mv0, fAll,
                                 Wih4, bih, bhh, keyLo, keyHi, prevA, Whh,
                                 Hh, Ch, gpre, p_W, p_b, out, prog);
}